// Round 1
// 2714.131 us; speedup vs baseline: 1.1065x; 1.1065x over previous
//
#include <hip/hip_runtime.h>
#include <hip/hip_bf16.h>
#include <stdint.h>

#define R_ 128
#define N_ 512
#define DIM_ 128
#define H_ 8
#define DP_ 128
#define INNER_ 256
#define RD_ 4096   // R*DH

typedef __hip_bfloat16 bf16;
typedef __attribute__((ext_vector_type(8))) short bfrag8;   // 8 bf16 (4 VGPRs)
typedef __attribute__((ext_vector_type(4))) float facc4;    // 4 fp32 acc

__device__ __forceinline__ float bf_lo(unsigned u) { return __uint_as_float(u << 16); }
__device__ __forceinline__ float bf_hi(unsigned u) { return __uint_as_float(u & 0xffff0000u); }

// ---------------------------------------------------------------------------
// Sentinel writer (interface diagnostics via absmax channel)
// ---------------------------------------------------------------------------
__global__ void k_sentinel(float* out, float v) { out[0] = v; }

// ---------------------------------------------------------------------------
// q_sw = x[0] @ Wq_sw + bq_sw  -> qsw [N][128] fp32   (once)
// ---------------------------------------------------------------------------
__global__ __launch_bounds__(128) void k_qsw(
    const float* __restrict__ x, const float* __restrict__ Wq_sw,
    const float* __restrict__ bq_sw, float* __restrict__ qsw)
{
    __shared__ float xr[128];
    const int n = blockIdx.x, t = threadIdx.x;
    xr[t] = x[(size_t)n * DIM_ + t];   // row r=0
    __syncthreads();
    float acc = bq_sw[t];
    for (int c = 0; c < 128; ++c) acc += xr[c] * Wq_sw[c * 128 + t];
    qsw[n * 128 + t] = acc;
}

// ---------------------------------------------------------------------------
// Per head: pair-bias LayerNorm + Wpair column h  -> dots [N][N] (pre-fill)
// ---------------------------------------------------------------------------
__global__ __launch_bounds__(256) void k_pb_h(
    const float* __restrict__ pb, const float* __restrict__ ln_g,
    const float* __restrict__ ln_b, const float* __restrict__ Wpair,
    float* __restrict__ dots, int h)
{
    __shared__ float sg[128], sb[128], wp[128];
    const int tid = threadIdx.x;
    if (tid < 128) { sg[tid] = ln_g[tid]; sb[tid] = ln_b[tid]; wp[tid] = Wpair[tid * 8 + h]; }
    __syncthreads();
    const int wave = tid >> 6, lane = tid & 63;
    const int flat = blockIdx.x * 4 + wave;    // i*N + j
    const float* pp = pb + (size_t)flat * DP_;
    float v0 = pp[lane], v1 = pp[lane + 64];
    float s = v0 + v1, ss = v0 * v0 + v1 * v1;
#pragma unroll
    for (int off = 32; off > 0; off >>= 1) {
        s  += __shfl_xor(s, off);
        ss += __shfl_xor(ss, off);
    }
    float mean = s * (1.0f / 128.0f);
    float var = ss * (1.0f / 128.0f) - mean * mean;
    float rs = rsqrtf(var + 1e-5f);
    float y0 = (v0 - mean) * rs * sg[lane] + sb[lane];
    float y1 = (v1 - mean) * rs * sg[lane + 64] + sb[lane + 64];
    float part = y0 * wp[lane] + y1 * wp[lane + 64];
#pragma unroll
    for (int off = 32; off > 0; off >>= 1) part += __shfl_xor(part, off);
    if (lane == 0) dots[flat] = part;
}

// ---------------------------------------------------------------------------
// Per head: sw[n][r] = dot16(qsw[n,h,:], x[r,n,:]@Wksw[:,h*16:]+b) * 0.25
// one thread per (n, r); fp32 end-to-end
// ---------------------------------------------------------------------------
__global__ __launch_bounds__(256) void k_sw_h(
    const float* __restrict__ x, const float* __restrict__ Wksw,
    const float* __restrict__ bksw, const float* __restrict__ qsw,
    float* __restrict__ sw, int h)
{
    const int idx = blockIdx.x * 256 + threadIdx.x;   // [0, 65536)
    const int n = idx >> 7, r = idx & 127;
    float acc[16];
#pragma unroll
    for (int d = 0; d < 16; ++d) acc[d] = bksw[h * 16 + d];
    const float* xr = x + (size_t)(r * N_ + n) * DIM_;
    for (int k = 0; k < 128; ++k) {
        float xv = xr[k];
        const float* wr = Wksw + k * 128 + h * 16;
#pragma unroll
        for (int d = 0; d < 16; ++d) acc[d] += xv * wr[d];
    }
    const float* qp = qsw + n * 128 + h * 16;
    float s = 0.0f;
#pragma unroll
    for (int d = 0; d < 16; ++d) s += acc[d] * qp[d];
    sw[n * 128 + r] = s * 0.25f;   // / sqrt(16 + 1e-8)
}

// ---------------------------------------------------------------------------
// softmax over r, in place on sw [N][R]
// ---------------------------------------------------------------------------
__global__ __launch_bounds__(128) void k_wrow2(float* __restrict__ sw)
{
    __shared__ float red[2];
    const int n = blockIdx.x, r = threadIdx.x;
    float s = sw[n * 128 + r];
    float m = s;
#pragma unroll
    for (int off = 32; off > 0; off >>= 1) m = fmaxf(m, __shfl_xor(m, off));
    if ((r & 63) == 0) red[r >> 6] = m;
    __syncthreads();
    m = fmaxf(red[0], red[1]);
    float e = __expf(s - m);
    float sum = e;
#pragma unroll
    for (int off = 32; off > 0; off >>= 1) sum += __shfl_xor(sum, off);
    __syncthreads();
    if ((r & 63) == 0) red[r >> 6] = sum;
    __syncthreads();
    sum = red[0] + red[1];
    sw[n * 128 + r] = e / sum;
}

// ---------------------------------------------------------------------------
// Simple 32-col projection per head: out = x @ W[:, col0:col0+32], bf16
// mode 0: out[(n*128 + r)*32 + d]   mode 1: out[(r*512 + n)*32 + d]
// rowW (optional): fp32 per-(n,r) weight applied before bf16 store (wrow fuse)
// ---------------------------------------------------------------------------
__global__ __launch_bounds__(256) void k_proj32(
    const float* __restrict__ x, const float* __restrict__ W,
    int ldw, int col0, bf16* __restrict__ out, int mode,
    const float* __restrict__ rowW)
{
    __shared__ float xs[8][128];
    const int tid = threadIdx.x;
    const int row0 = blockIdx.x * 8;
#pragma unroll
    for (int l = 0; l < 4; ++l) {
        int idx = l * 256 + tid;
        int m = idx >> 7, k = idx & 127;
        xs[m][k] = x[(size_t)(row0 + m) * DIM_ + k];
    }
    __syncthreads();
    const int m = tid >> 5, d = tid & 31;
    float acc = 0.0f;
    for (int k = 0; k < 128; ++k) acc += xs[m][k] * W[k * ldw + col0 + d];
    const int rowg = row0 + m;
    const int r = rowg >> 9, n = rowg & (N_ - 1);
    if (rowW) acc *= rowW[n * 128 + r];
    size_t o = (mode == 0) ? ((size_t)n * 128 + r) * 32 + d
                           : ((size_t)r * 512 + n) * 32 + d;
    out[o] = __float2bfloat16(acc);
}

// ---------------------------------------------------------------------------
// Per head (MFMA): dots[i][j] += scale * sum_rd q_h[i][rd] * k_h[j][rd]
// q_h is pre-scaled by wrow (fused into k_proj32).
// Grid (8,8) of 64x64 C-tiles, 4 waves/block, each wave a 2x2 quad of
// 16x16x32 bf16 MFMA tiles. No LDS: lane l loads 8 contiguous bf16 from
// row (l&15) at k-offset (l>>4)*8 -- operands are L2-resident (written by
// k_proj32 just before).
// ---------------------------------------------------------------------------
__global__ __launch_bounds__(256) void k_dots_mfma(
    const bf16* __restrict__ q_h, const bf16* __restrict__ k_h,
    float* __restrict__ dots)
{
    const int tid  = threadIdx.x;
    const int wave = tid >> 6, lane = tid & 63;
    const int i0 = blockIdx.y * 64 + (wave >> 1) * 32;
    const int j0 = blockIdx.x * 64 + (wave & 1) * 32;
    const int lr = lane & 15;          // row within 16-tile
    const int lk = (lane >> 4) * 8;    // k offset within 32-chunk

    const bf16* a0p = q_h + (((size_t)(i0 + lr))      << 12) + lk;
    const bf16* a1p = q_h + (((size_t)(i0 + 16 + lr)) << 12) + lk;
    const bf16* b0p = k_h + (((size_t)(j0 + lr))      << 12) + lk;
    const bf16* b1p = k_h + (((size_t)(j0 + 16 + lr)) << 12) + lk;

    facc4 acc00 = {}, acc01 = {}, acc10 = {}, acc11 = {};

#pragma unroll 4
    for (int k = 0; k < RD_; k += 32) {
        bfrag8 a0 = *(const bfrag8*)(a0p + k);
        bfrag8 a1 = *(const bfrag8*)(a1p + k);
        bfrag8 b0 = *(const bfrag8*)(b0p + k);
        bfrag8 b1 = *(const bfrag8*)(b1p + k);
        acc00 = __builtin_amdgcn_mfma_f32_16x16x32_bf16(a0, b0, acc00, 0, 0, 0);
        acc01 = __builtin_amdgcn_mfma_f32_16x16x32_bf16(a0, b1, acc01, 0, 0, 0);
        acc10 = __builtin_amdgcn_mfma_f32_16x16x32_bf16(a1, b0, acc10, 0, 0, 0);
        acc11 = __builtin_amdgcn_mfma_f32_16x16x32_bf16(a1, b1, acc11, 0, 0, 0);
    }

    const float scale = 0.17677669529663689f;   // 32^-0.5
    // C/D layout: col = lane&15, row = (lane>>4)*4 + t   [m89-verified]
    const int dr = (lane >> 4) * 4, dc = lane & 15;
#pragma unroll
    for (int t = 0; t < 4; ++t) {
        dots[(size_t)(i0 +      dr + t) * N_ + (j0 +      dc)] += acc00[t] * scale;
        dots[(size_t)(i0 +      dr + t) * N_ + (j0 + 16 + dc)] += acc01[t] * scale;
        dots[(size_t)(i0 + 16 + dr + t) * N_ + (j0 +      dc)] += acc10[t] * scale;
        dots[(size_t)(i0 + 16 + dr + t) * N_ + (j0 + 16 + dc)] += acc11[t] * scale;
    }
}

// ---------------------------------------------------------------------------
// row softmax over j, in place on dots [N][N]
// ---------------------------------------------------------------------------
__global__ __launch_bounds__(256) void k_smax(float* __restrict__ dots)
{
    __shared__ float red[4];
    const int i = blockIdx.x;
    const int t = threadIdx.x;
    float* p = dots + (size_t)i * N_;
    float a = p[t], b = p[t + 256];
    float m = fmaxf(a, b);
#pragma unroll
    for (int off = 32; off > 0; off >>= 1) m = fmaxf(m, __shfl_xor(m, off));
    if ((t & 63) == 0) red[t >> 6] = m;
    __syncthreads();
    m = fmaxf(fmaxf(red[0], red[1]), fmaxf(red[2], red[3]));
    float e0 = __expf(a - m), e1 = __expf(b - m);
    float s = e0 + e1;
#pragma unroll
    for (int off = 32; off > 0; off >>= 1) s += __shfl_xor(s, off);
    __syncthreads();
    if ((t & 63) == 0) red[t >> 6] = s;
    __syncthreads();
    s = red[0] + red[1] + red[2] + red[3];
    float inv = 1.0f / s;
    p[t] = e0 * inv;
    p[t + 256] = e1 * inv;
}

// ---------------------------------------------------------------------------
// Per head: om[r][i][h*32+d] = sum_j attn[i][j] * v_h[r][j][d]
// grid (8 it, 128 r); om (bf16) lives in d_out
// ---------------------------------------------------------------------------
__global__ __launch_bounds__(256) void k_av_h(
    const float* __restrict__ attn, const bf16* __restrict__ v_h,
    bf16* __restrict__ om, int h)
{
    __shared__ float as[64][66];   // [i][j]
    __shared__ float vs[64][34];   // [j][d]
    const int tid = threadIdx.x;
    const int it = blockIdx.x, r = blockIdx.y;
    const int i0 = it * 64;
    const int ti = tid >> 4, td = tid & 15;
    float acc[4][2] = {};

    for (int j0 = 0; j0 < N_; j0 += 64) {
#pragma unroll
        for (int l = 0; l < 4; ++l) {
            int idx = l * 256 + tid;
            int i = idx >> 4, j4 = idx & 15;
            float4 u = *(const float4*)(attn + (size_t)(i0 + i) * N_ + j0 + j4 * 4);
            float* d = &as[i][j4 * 4];
            d[0] = u.x; d[1] = u.y; d[2] = u.z; d[3] = u.w;
        }
        {
            int j = tid >> 2, ck = tid & 3;
            uint4 u = *(const uint4*)(v_h + ((size_t)r * N_ + j0 + j) * 32 + ck * 8);
            float* d = &vs[j][ck * 8];
            d[0] = bf_lo(u.x); d[1] = bf_hi(u.x); d[2] = bf_lo(u.y); d[3] = bf_hi(u.y);
            d[4] = bf_lo(u.z); d[5] = bf_hi(u.z); d[6] = bf_lo(u.w); d[7] = bf_hi(u.w);
        }
        __syncthreads();
#pragma unroll 8
        for (int jj = 0; jj < 64; jj += 2) {
            float2 b0 = *(const float2*)&vs[jj][td * 2];
            float2 b1 = *(const float2*)&vs[jj + 1][td * 2];
#pragma unroll
            for (int i = 0; i < 4; ++i) {
                float2 a = *(const float2*)&as[ti * 4 + i][jj];
                acc[i][0] += a.x * b0.x + a.y * b1.x;
                acc[i][1] += a.x * b0.y + a.y * b1.y;
            }
        }
        __syncthreads();
    }
#pragma unroll
    for (int ii = 0; ii < 4; ++ii) {
        bf16* op = om + ((size_t)r * N_ + i0 + ti * 4 + ii) * INNER_ + h * 32 + td * 2;
        op[0] = __float2bfloat16(acc[ii][0]);
        op[1] = __float2bfloat16(acc[ii][1]);
    }
}

// ---------------------------------------------------------------------------
// out = om @ Wout + b_out, IN PLACE on d_out (om bf16 -> out fp32).
// Block owns 64 full rows; om row bytes == out row bytes -> in-place safe.
// ---------------------------------------------------------------------------
__global__ __launch_bounds__(256) void k_final(
    const bf16* om, const float* __restrict__ Wout,
    const float* __restrict__ b_out, float* out)
{
    __shared__ float as[64][68];
    __shared__ float ws[64][132];
    const int tid = threadIdx.x;
    const int row0 = blockIdx.x * 64;
    const int tm = tid >> 5, tc = tid & 31;
    float acc[8][4] = {};

    for (int k0 = 0; k0 < INNER_; k0 += 64) {
#pragma unroll
        for (int l = 0; l < 2; ++l) {
            int idx = l * 256 + tid;
            int m = idx >> 3, ck = idx & 7;
            uint4 u = *(const uint4*)(om + (size_t)(row0 + m) * INNER_ + k0 + ck * 8);
            float* d = &as[m][ck * 8];
            d[0] = bf_lo(u.x); d[1] = bf_hi(u.x); d[2] = bf_lo(u.y); d[3] = bf_hi(u.y);
            d[4] = bf_lo(u.z); d[5] = bf_hi(u.z); d[6] = bf_lo(u.w); d[7] = bf_hi(u.w);
        }
#pragma unroll
        for (int l = 0; l < 8; ++l) {
            int idx = l * 256 + tid;
            int kk = idx >> 5, c4 = idx & 31;
            float4 u = *(const float4*)(Wout + (size_t)(k0 + kk) * DIM_ + c4 * 4);
            float* d = &ws[kk][c4 * 4];
            d[0] = u.x; d[1] = u.y; d[2] = u.z; d[3] = u.w;
        }
        __syncthreads();
        for (int kk = 0; kk < 64; kk += 2) {
            float4 b0 = *(const float4*)&ws[kk][tc * 4];
            float4 b1 = *(const float4*)&ws[kk + 1][tc * 4];
#pragma unroll
            for (int i = 0; i < 8; ++i) {
                float2 a = *(const float2*)&as[tm * 8 + i][kk];
                acc[i][0] += a.x * b0.x + a.y * b1.x;
                acc[i][1] += a.x * b0.y + a.y * b1.y;
                acc[i][2] += a.x * b0.z + a.y * b1.z;
                acc[i][3] += a.x * b0.w + a.y * b1.w;
            }
        }
        __syncthreads();
    }
#pragma unroll
    for (int ii = 0; ii < 8; ++ii) {
        int rowg = row0 + tm * 8 + ii;
#pragma unroll
        for (int jj = 0; jj < 4; ++jj) {
            int cg = tc * 4 + jj;
            out[(size_t)rowg * DIM_ + cg] = acc[ii][jj] + b_out[cg];
        }
    }
}

// ---------------------------------------------------------------------------
// Workspace arena — high-water mark 9,961,472 B (9.5 MiB):
//   [0        ..  1,048,576)  dots  [N][N] fp32 (pb prefill -> +qk -> softmax in place)
//   [1,048,576..  1,310,720)  sw    [N][R] fp32 (-> wrow in place)
//   [1,310,720..  1,572,864)  qsw   [N][128] fp32
//   [1,572,864..  5,767,168)  q_h   [N][R][32] bf16 (pre-scaled by wrow)
//   [5,767,168..  9,961,472)  k_h   [N][R][32] bf16, later aliased by v_h [R][N][32]
// om (bf16, 33.55 MB) lives in d_out; k_final converts to fp32 in place.
// ---------------------------------------------------------------------------
extern "C" void kernel_launch(void* const* d_in, const int* in_sizes, int n_in,
                              void* d_out, int out_size, void* d_ws, size_t ws_size,
                              hipStream_t stream)
{
    // ---- interface guards: report anomalies through the absmax channel ----
    static const int exp_sizes[13] = {8388608, 33554432, 32768, 65536, 32768,
                                      128, 128, 128, 1024, 16384, 128, 16384, 128};
    const size_t WS_NEED = 9961472ULL;
    float sentinel = 0.0f;
    if (n_in != 13) sentinel = 5e7f;
    else {
        for (int i = 0; i < 13; ++i)
            if (in_sizes[i] != exp_sizes[i]) { sentinel = 1e6f * (float)(i + 1); break; }
    }
    if (sentinel == 0.0f && out_size != 8388608) sentinel = 6e7f;
    if (sentinel == 0.0f && ws_size < WS_NEED) sentinel = 1e8f + (float)ws_size;
    if (sentinel != 0.0f) {
        k_sentinel<<<1, 1, 0, stream>>>((float*)d_out, sentinel);
        return;
    }

    const float* x     = (const float*)d_in[0];
    const float* pair  = (const float*)d_in[1];
    const float* Wq    = (const float*)d_in[2];
    const float* Wkv   = (const float*)d_in[3];
    const float* Wout  = (const float*)d_in[4];
    const float* b_out = (const float*)d_in[5];
    const float* ln_g  = (const float*)d_in[6];
    const float* ln_b  = (const float*)d_in[7];
    const float* Wpair = (const float*)d_in[8];
    const float* Wq_sw = (const float*)d_in[9];
    const float* bq_sw = (const float*)d_in[10];
    const float* Wk_sw = (const float*)d_in[11];
    const float* bk_sw = (const float*)d_in[12];

    char* w = (char*)d_ws;
    float* dots = (float*)(w);
    float* sw   = (float*)(w + 1048576ULL);
    float* qsw  = (float*)(w + 1310720ULL);
    bf16*  q_h  = (bf16*)(w + 1572864ULL);
    bf16*  k_h  = (bf16*)(w + 5767168ULL);
    bf16*  v_h  = k_h;                     // aliases k_h (k dead after k_dots_mfma)
    bf16*  om   = (bf16*)d_out;

    k_qsw<<<dim3(512), 128, 0, stream>>>(x, Wq_sw, bq_sw, qsw);

    for (int h = 0; h < H_; ++h) {
        k_pb_h  <<<dim3(65536),   256, 0, stream>>>(pair, ln_g, ln_b, Wpair, dots, h);
        k_sw_h  <<<dim3(256),     256, 0, stream>>>(x, Wk_sw, bk_sw, qsw, sw, h);
        k_wrow2 <<<dim3(512),     128, 0, stream>>>(sw);
        // q projection with wrow fused (pre-scaled bf16 A-operand for MFMA)
        k_proj32<<<dim3(8192),    256, 0, stream>>>(x, Wq,  256, h * 32,       q_h, 0, sw);
        k_proj32<<<dim3(8192),    256, 0, stream>>>(x, Wkv, 512, h * 32,       k_h, 0, nullptr);
        k_dots_mfma<<<dim3(8, 8), 256, 0, stream>>>(q_h, k_h, dots);
        k_smax  <<<dim3(512),     256, 0, stream>>>(dots);
        k_proj32<<<dim3(8192),    256, 0, stream>>>(x, Wkv, 512, 256 + h * 32, v_h, 1, nullptr);
        k_av_h  <<<dim3(8, 128),  256, 0, stream>>>(dots, v_h, om, h);
    }

    k_final<<<dim3(1024), 256, 0, stream>>>(om, Wout, b_out, (float*)d_out);
}

// Round 2
// 2280.455 us; speedup vs baseline: 1.3169x; 1.1902x over previous
//
#include <hip/hip_runtime.h>
#include <hip/hip_bf16.h>
#include <stdint.h>

#define R_ 128
#define N_ 512
#define DIM_ 128
#define H_ 8
#define DP_ 128
#define INNER_ 256
#define RD_ 4096   // R*DH
#define NN_ 262144 // N*N

typedef __hip_bfloat16 bf16;
typedef __attribute__((ext_vector_type(8))) short bfrag8;   // 8 bf16 (4 VGPRs)
typedef __attribute__((ext_vector_type(4))) float facc4;    // 4 fp32 acc

__device__ __forceinline__ float bf_lo(unsigned u) { return __uint_as_float(u << 16); }
__device__ __forceinline__ float bf_hi(unsigned u) { return __uint_as_float(u & 0xffff0000u); }

// ---------------------------------------------------------------------------
// Sentinel writer (interface diagnostics via absmax channel)
// ---------------------------------------------------------------------------
__global__ void k_sentinel(float* out, float v) { out[0] = v; }

// ---------------------------------------------------------------------------
// q_sw = x[0] @ Wq_sw + bq_sw  -> qsw [N][128] fp32   (once)
// ---------------------------------------------------------------------------
__global__ __launch_bounds__(128) void k_qsw(
    const float* __restrict__ x, const float* __restrict__ Wq_sw,
    const float* __restrict__ bq_sw, float* __restrict__ qsw)
{
    __shared__ float xr[128];
    const int n = blockIdx.x, t = threadIdx.x;
    xr[t] = x[(size_t)n * DIM_ + t];   // row r=0
    __syncthreads();
    float acc = bq_sw[t];
    for (int c = 0; c < 128; ++c) acc += xr[c] * Wq_sw[c * 128 + t];
    qsw[n * 128 + t] = acc;
}

// ---------------------------------------------------------------------------
// ONE PASS pair-bias: LayerNorm + Wpair (all 8 heads) -> pbh [8][N][N] fp32
// One wave per (i,j) row of pb; 8-head dot reduced with a packed butterfly.
// ---------------------------------------------------------------------------
__global__ __launch_bounds__(256) void k_pb_all(
    const float* __restrict__ pb, const float* __restrict__ ln_g,
    const float* __restrict__ ln_b, const float* __restrict__ Wpair,
    float* __restrict__ pbh)
{
    __shared__ float sg[128], sb[128], wp[128][8];
    const int tid = threadIdx.x;
    if (tid < 128) { sg[tid] = ln_g[tid]; sb[tid] = ln_b[tid]; }
#pragma unroll
    for (int l = 0; l < 4; ++l) {
        int idx = l * 256 + tid;            // 0..1023
        wp[idx >> 3][idx & 7] = Wpair[idx]; // Wpair[c][h]
    }
    __syncthreads();
    const int wave = tid >> 6, lane = tid & 63;
    const int flat = blockIdx.x * 4 + wave;    // i*N + j
    const float* pp = pb + (size_t)flat * DP_;
    float v0 = pp[lane], v1 = pp[lane + 64];
    float s = v0 + v1, ss = v0 * v0 + v1 * v1;
#pragma unroll
    for (int off = 32; off > 0; off >>= 1) {
        s  += __shfl_xor(s, off);
        ss += __shfl_xor(ss, off);
    }
    float mean = s * (1.0f / 128.0f);
    float var = ss * (1.0f / 128.0f) - mean * mean;
    float rs = rsqrtf(var + 1e-5f);
    float y0 = (v0 - mean) * rs * sg[lane] + sb[lane];
    float y1 = (v1 - mean) * rs * sg[lane + 64] + sb[lane + 64];
    float p[8];
#pragma unroll
    for (int hh = 0; hh < 8; ++hh)
        p[hh] = y0 * wp[lane][hh] + y1 * wp[lane + 64][hh];
#pragma unroll
    for (int off = 32; off > 0; off >>= 1) {
#pragma unroll
        for (int hh = 0; hh < 8; ++hh) p[hh] += __shfl_xor(p[hh], off);
    }
    if (lane == 0) {
#pragma unroll
        for (int hh = 0; hh < 8; ++hh)   // static indexing (no scratch)
            pbh[(size_t)hh * NN_ + flat] = p[hh];
    }
}

// ---------------------------------------------------------------------------
// FALLBACK: per-head pair-bias LayerNorm + Wpair column h -> dots prefill
// ---------------------------------------------------------------------------
__global__ __launch_bounds__(256) void k_pb_h(
    const float* __restrict__ pb, const float* __restrict__ ln_g,
    const float* __restrict__ ln_b, const float* __restrict__ Wpair,
    float* __restrict__ dots, int h)
{
    __shared__ float sg[128], sb[128], wp[128];
    const int tid = threadIdx.x;
    if (tid < 128) { sg[tid] = ln_g[tid]; sb[tid] = ln_b[tid]; wp[tid] = Wpair[tid * 8 + h]; }
    __syncthreads();
    const int wave = tid >> 6, lane = tid & 63;
    const int flat = blockIdx.x * 4 + wave;    // i*N + j
    const float* pp = pb + (size_t)flat * DP_;
    float v0 = pp[lane], v1 = pp[lane + 64];
    float s = v0 + v1, ss = v0 * v0 + v1 * v1;
#pragma unroll
    for (int off = 32; off > 0; off >>= 1) {
        s  += __shfl_xor(s, off);
        ss += __shfl_xor(ss, off);
    }
    float mean = s * (1.0f / 128.0f);
    float var = ss * (1.0f / 128.0f) - mean * mean;
    float rs = rsqrtf(var + 1e-5f);
    float y0 = (v0 - mean) * rs * sg[lane] + sb[lane];
    float y1 = (v1 - mean) * rs * sg[lane + 64] + sb[lane + 64];
    float part = y0 * wp[lane] + y1 * wp[lane + 64];
#pragma unroll
    for (int off = 32; off > 0; off >>= 1) part += __shfl_xor(part, off);
    if (lane == 0) dots[flat] = part;
}

// ---------------------------------------------------------------------------
// Per head: sw[n][r] = dot16(qsw[n,h,:], x[r,n,:]@Wksw[:,h*16:]+b) * 0.25
// one thread per (n, r); fp32 end-to-end
// ---------------------------------------------------------------------------
__global__ __launch_bounds__(256) void k_sw_h(
    const float* __restrict__ x, const float* __restrict__ Wksw,
    const float* __restrict__ bksw, const float* __restrict__ qsw,
    float* __restrict__ sw, int h)
{
    const int idx = blockIdx.x * 256 + threadIdx.x;   // [0, 65536)
    const int n = idx >> 7, r = idx & 127;
    float acc[16];
#pragma unroll
    for (int d = 0; d < 16; ++d) acc[d] = bksw[h * 16 + d];
    const float* xr = x + (size_t)(r * N_ + n) * DIM_;
    for (int k = 0; k < 128; ++k) {
        float xv = xr[k];
        const float* wr = Wksw + k * 128 + h * 16;
#pragma unroll
        for (int d = 0; d < 16; ++d) acc[d] += xv * wr[d];
    }
    const float* qp = qsw + n * 128 + h * 16;
    float s = 0.0f;
#pragma unroll
    for (int d = 0; d < 16; ++d) s += acc[d] * qp[d];
    sw[n * 128 + r] = s * 0.25f;   // / sqrt(16 + 1e-8)
}

// ---------------------------------------------------------------------------
// softmax over r, in place on sw [N][R]
// ---------------------------------------------------------------------------
__global__ __launch_bounds__(128) void k_wrow2(float* __restrict__ sw)
{
    __shared__ float red[2];
    const int n = blockIdx.x, r = threadIdx.x;
    float s = sw[n * 128 + r];
    float m = s;
#pragma unroll
    for (int off = 32; off > 0; off >>= 1) m = fmaxf(m, __shfl_xor(m, off));
    if ((r & 63) == 0) red[r >> 6] = m;
    __syncthreads();
    m = fmaxf(red[0], red[1]);
    float e = __expf(s - m);
    float sum = e;
#pragma unroll
    for (int off = 32; off > 0; off >>= 1) sum += __shfl_xor(sum, off);
    __syncthreads();
    if ((r & 63) == 0) red[r >> 6] = sum;
    __syncthreads();
    sum = red[0] + red[1];
    sw[n * 128 + r] = e / sum;
}

// ---------------------------------------------------------------------------
// Merged per-head projection: q, k, v in ONE x pass.
//   q -> [(n*128+r)*32+d] bf16 (scaled by wrow)
//   k -> [(n*128+r)*32+d] bf16
//   v -> [(r*512+n)*32+d] bf16
// ---------------------------------------------------------------------------
__global__ __launch_bounds__(256) void k_proj96(
    const float* __restrict__ x, const float* __restrict__ Wq,
    const float* __restrict__ Wkv, int h, const float* __restrict__ rowW,
    bf16* __restrict__ qo, bf16* __restrict__ ko, bf16* __restrict__ vo)
{
    __shared__ float xs[8][128];
    const int tid = threadIdx.x;
    const int row0 = blockIdx.x * 8;
#pragma unroll
    for (int l = 0; l < 4; ++l) {
        int idx = l * 256 + tid;
        int m = idx >> 7, k = idx & 127;
        xs[m][k] = x[(size_t)(row0 + m) * DIM_ + k];
    }
    __syncthreads();
    const int m = tid >> 5, d = tid & 31;
    const float* wq = Wq  + h * 32 + d;         // stride 256
    const float* wk = Wkv + h * 32 + d;         // stride 512
    const float* wv = Wkv + 256 + h * 32 + d;   // stride 512
    float aq = 0.0f, ak = 0.0f, av = 0.0f;
    for (int k = 0; k < 128; ++k) {
        float xv = xs[m][k];
        aq += xv * wq[k * 256];
        ak += xv * wk[k * 512];
        av += xv * wv[k * 512];
    }
    const int rowg = row0 + m;
    const int r = rowg >> 9, n = rowg & (N_ - 1);
    aq *= rowW[n * 128 + r];
    qo[((size_t)n * 128 + r) * 32 + d] = __float2bfloat16(aq);
    ko[((size_t)n * 128 + r) * 32 + d] = __float2bfloat16(ak);
    vo[((size_t)r * 512 + n) * 32 + d] = __float2bfloat16(av);
}

// ---------------------------------------------------------------------------
// FALLBACK: single 32-col projection per head
// ---------------------------------------------------------------------------
__global__ __launch_bounds__(256) void k_proj32(
    const float* __restrict__ x, const float* __restrict__ W,
    int ldw, int col0, bf16* __restrict__ out, int mode,
    const float* __restrict__ rowW)
{
    __shared__ float xs[8][128];
    const int tid = threadIdx.x;
    const int row0 = blockIdx.x * 8;
#pragma unroll
    for (int l = 0; l < 4; ++l) {
        int idx = l * 256 + tid;
        int m = idx >> 7, k = idx & 127;
        xs[m][k] = x[(size_t)(row0 + m) * DIM_ + k];
    }
    __syncthreads();
    const int m = tid >> 5, d = tid & 31;
    float acc = 0.0f;
    for (int k = 0; k < 128; ++k) acc += xs[m][k] * W[k * ldw + col0 + d];
    const int rowg = row0 + m;
    const int r = rowg >> 9, n = rowg & (N_ - 1);
    if (rowW) acc *= rowW[n * 128 + r];
    size_t o = (mode == 0) ? ((size_t)n * 128 + r) * 32 + d
                           : ((size_t)r * 512 + n) * 32 + d;
    out[o] = __float2bfloat16(acc);
}

// ---------------------------------------------------------------------------
// Per head (MFMA): dots[i][j] = base[i][j] + scale * sum_rd q[i][rd]*k[j][rd]
// base = pbh plane (big path) or dots itself (fallback: in-place add).
// Grid (8,8) of 64x64 C-tiles, 4 waves/block, 2x2 quad of 16x16x32 MFMA.
// ---------------------------------------------------------------------------
__global__ __launch_bounds__(256) void k_dots_mfma(
    const bf16* __restrict__ q_h, const bf16* __restrict__ k_h,
    const float* base, float* dots)
{
    const int tid  = threadIdx.x;
    const int wave = tid >> 6, lane = tid & 63;
    const int i0 = blockIdx.y * 64 + (wave >> 1) * 32;
    const int j0 = blockIdx.x * 64 + (wave & 1) * 32;
    const int lr = lane & 15;          // row within 16-tile
    const int lk = (lane >> 4) * 8;    // k offset within 32-chunk

    const bf16* a0p = q_h + (((size_t)(i0 + lr))      << 12) + lk;
    const bf16* a1p = q_h + (((size_t)(i0 + 16 + lr)) << 12) + lk;
    const bf16* b0p = k_h + (((size_t)(j0 + lr))      << 12) + lk;
    const bf16* b1p = k_h + (((size_t)(j0 + 16 + lr)) << 12) + lk;

    facc4 acc00 = {}, acc01 = {}, acc10 = {}, acc11 = {};

#pragma unroll 4
    for (int k = 0; k < RD_; k += 32) {
        bfrag8 a0 = *(const bfrag8*)(a0p + k);
        bfrag8 a1 = *(const bfrag8*)(a1p + k);
        bfrag8 b0 = *(const bfrag8*)(b0p + k);
        bfrag8 b1 = *(const bfrag8*)(b1p + k);
        acc00 = __builtin_amdgcn_mfma_f32_16x16x32_bf16(a0, b0, acc00, 0, 0, 0);
        acc01 = __builtin_amdgcn_mfma_f32_16x16x32_bf16(a0, b1, acc01, 0, 0, 0);
        acc10 = __builtin_amdgcn_mfma_f32_16x16x32_bf16(a1, b0, acc10, 0, 0, 0);
        acc11 = __builtin_amdgcn_mfma_f32_16x16x32_bf16(a1, b1, acc11, 0, 0, 0);
    }

    const float scale = 0.17677669529663689f;   // 32^-0.5
    // C/D layout: col = lane&15, row = (lane>>4)*4 + t   [m89-verified]
    const int dr = (lane >> 4) * 4, dc = lane & 15;
#pragma unroll
    for (int t = 0; t < 4; ++t) {
        size_t i00 = (size_t)(i0 +      dr + t) * N_;
        size_t i16 = (size_t)(i0 + 16 + dr + t) * N_;
        dots[i00 + j0 +      dc] = base[i00 + j0 +      dc] + acc00[t] * scale;
        dots[i00 + j0 + 16 + dc] = base[i00 + j0 + 16 + dc] + acc01[t] * scale;
        dots[i16 + j0 +      dc] = base[i16 + j0 +      dc] + acc10[t] * scale;
        dots[i16 + j0 + 16 + dc] = base[i16 + j0 + 16 + dc] + acc11[t] * scale;
    }
}

// ---------------------------------------------------------------------------
// row softmax over j, in place on dots [N][N]
// ---------------------------------------------------------------------------
__global__ __launch_bounds__(256) void k_smax(float* __restrict__ dots)
{
    __shared__ float red[4];
    const int i = blockIdx.x;
    const int t = threadIdx.x;
    float* p = dots + (size_t)i * N_;
    float a = p[t], b = p[t + 256];
    float m = fmaxf(a, b);
#pragma unroll
    for (int off = 32; off > 0; off >>= 1) m = fmaxf(m, __shfl_xor(m, off));
    if ((t & 63) == 0) red[t >> 6] = m;
    __syncthreads();
    m = fmaxf(fmaxf(red[0], red[1]), fmaxf(red[2], red[3]));
    float e0 = __expf(a - m), e1 = __expf(b - m);
    float s = e0 + e1;
#pragma unroll
    for (int off = 32; off > 0; off >>= 1) s += __shfl_xor(s, off);
    __syncthreads();
    if ((t & 63) == 0) red[t >> 6] = s;
    __syncthreads();
    s = red[0] + red[1] + red[2] + red[3];
    float inv = 1.0f / s;
    p[t] = e0 * inv;
    p[t + 256] = e1 * inv;
}

// ---------------------------------------------------------------------------
// Per head: om[r][i][h*32+d] = sum_j attn[i][j] * v_h[r][j][d]
// grid (8 it, 128 r); om (bf16) lives in d_out
// ---------------------------------------------------------------------------
__global__ __launch_bounds__(256) void k_av_h(
    const float* __restrict__ attn, const bf16* __restrict__ v_h,
    bf16* __restrict__ om, int h)
{
    __shared__ float as[64][66];   // [i][j]
    __shared__ float vs[64][34];   // [j][d]
    const int tid = threadIdx.x;
    const int it = blockIdx.x, r = blockIdx.y;
    const int i0 = it * 64;
    const int ti = tid >> 4, td = tid & 15;
    float acc[4][2] = {};

    for (int j0 = 0; j0 < N_; j0 += 64) {
#pragma unroll
        for (int l = 0; l < 4; ++l) {
            int idx = l * 256 + tid;
            int i = idx >> 4, j4 = idx & 15;
            float4 u = *(const float4*)(attn + (size_t)(i0 + i) * N_ + j0 + j4 * 4);
            float* d = &as[i][j4 * 4];
            d[0] = u.x; d[1] = u.y; d[2] = u.z; d[3] = u.w;
        }
        {
            int j = tid >> 2, ck = tid & 3;
            uint4 u = *(const uint4*)(v_h + ((size_t)r * N_ + j0 + j) * 32 + ck * 8);
            float* d = &vs[j][ck * 8];
            d[0] = bf_lo(u.x); d[1] = bf_hi(u.x); d[2] = bf_lo(u.y); d[3] = bf_hi(u.y);
            d[4] = bf_lo(u.z); d[5] = bf_hi(u.z); d[6] = bf_lo(u.w); d[7] = bf_hi(u.w);
        }
        __syncthreads();
#pragma unroll 8
        for (int jj = 0; jj < 64; jj += 2) {
            float2 b0 = *(const float2*)&vs[jj][td * 2];
            float2 b1 = *(const float2*)&vs[jj + 1][td * 2];
#pragma unroll
            for (int i = 0; i < 4; ++i) {
                float2 a = *(const float2*)&as[ti * 4 + i][jj];
                acc[i][0] += a.x * b0.x + a.y * b1.x;
                acc[i][1] += a.x * b0.y + a.y * b1.y;
            }
        }
        __syncthreads();
    }
#pragma unroll
    for (int ii = 0; ii < 4; ++ii) {
        bf16* op = om + ((size_t)r * N_ + i0 + ti * 4 + ii) * INNER_ + h * 32 + td * 2;
        op[0] = __float2bfloat16(acc[ii][0]);
        op[1] = __float2bfloat16(acc[ii][1]);
    }
}

// ---------------------------------------------------------------------------
// out = om @ Wout + b_out, IN PLACE on d_out (om bf16 -> out fp32).
// ---------------------------------------------------------------------------
__global__ __launch_bounds__(256) void k_final(
    const bf16* om, const float* __restrict__ Wout,
    const float* __restrict__ b_out, float* out)
{
    __shared__ float as[64][68];
    __shared__ float ws[64][132];
    const int tid = threadIdx.x;
    const int row0 = blockIdx.x * 64;
    const int tm = tid >> 5, tc = tid & 31;
    float acc[8][4] = {};

    for (int k0 = 0; k0 < INNER_; k0 += 64) {
#pragma unroll
        for (int l = 0; l < 2; ++l) {
            int idx = l * 256 + tid;
            int m = idx >> 3, ck = idx & 7;
            uint4 u = *(const uint4*)(om + (size_t)(row0 + m) * INNER_ + k0 + ck * 8);
            float* d = &as[m][ck * 8];
            d[0] = bf_lo(u.x); d[1] = bf_hi(u.x); d[2] = bf_lo(u.y); d[3] = bf_hi(u.y);
            d[4] = bf_lo(u.z); d[5] = bf_hi(u.z); d[6] = bf_lo(u.w); d[7] = bf_hi(u.w);
        }
#pragma unroll
        for (int l = 0; l < 8; ++l) {
            int idx = l * 256 + tid;
            int kk = idx >> 5, c4 = idx & 31;
            float4 u = *(const float4*)(Wout + (size_t)(k0 + kk) * DIM_ + c4 * 4);
            float* d = &ws[kk][c4 * 4];
            d[0] = u.x; d[1] = u.y; d[2] = u.z; d[3] = u.w;
        }
        __syncthreads();
        for (int kk = 0; kk < 64; kk += 2) {
            float4 b0 = *(const float4*)&ws[kk][tc * 4];
            float4 b1 = *(const float4*)&ws[kk + 1][tc * 4];
#pragma unroll
            for (int i = 0; i < 8; ++i) {
                float2 a = *(const float2*)&as[tm * 8 + i][kk];
                acc[i][0] += a.x * b0.x + a.y * b1.x;
                acc[i][1] += a.x * b0.y + a.y * b1.y;
                acc[i][2] += a.x * b0.z + a.y * b1.z;
                acc[i][3] += a.x * b0.w + a.y * b1.w;
            }
        }
        __syncthreads();
    }
#pragma unroll
    for (int ii = 0; ii < 8; ++ii) {
        int rowg = row0 + tm * 8 + ii;
#pragma unroll
        for (int jj = 0; jj < 4; ++jj) {
            int cg = tc * 4 + jj;
            out[(size_t)rowg * DIM_ + cg] = acc[ii][jj] + b_out[cg];
        }
    }
}

// ---------------------------------------------------------------------------
// Workspace arena.
// BIG path (ws >= 22,544,384 B):
//   [0        ..  1,048,576)  dots [N][N] fp32
//   [1,048,576..  1,310,720)  sw   [N][R] fp32 (-> wrow in place)
//   [1,310,720..  1,572,864)  qsw  [N][128] fp32
//   [1,572,864..  5,767,168)  q_h  [N][R][32] bf16 (pre-scaled by wrow)
//   [5,767,168..  9,961,472)  k_h  [N][R][32] bf16
//   [9,961,472.. 14,155,776)  v_h  [R][N][32] bf16
//   [14,155,776..22,544,384)  pbh  [8][N][N] fp32 (LN+Wpair, all heads, once)
// FALLBACK (ws >= 9,961,472): previous-round layout, per-head k_pb_h,
//   3x k_proj32, v aliases k.
// om (bf16, 33.55 MB) lives in d_out; k_final converts to fp32 in place.
// ---------------------------------------------------------------------------
extern "C" void kernel_launch(void* const* d_in, const int* in_sizes, int n_in,
                              void* d_out, int out_size, void* d_ws, size_t ws_size,
                              hipStream_t stream)
{
    static const int exp_sizes[13] = {8388608, 33554432, 32768, 65536, 32768,
                                      128, 128, 128, 1024, 16384, 128, 16384, 128};
    const size_t WS_MIN = 9961472ULL;
    const size_t WS_BIG = 22544384ULL;
    float sentinel = 0.0f;
    if (n_in != 13) sentinel = 5e7f;
    else {
        for (int i = 0; i < 13; ++i)
            if (in_sizes[i] != exp_sizes[i]) { sentinel = 1e6f * (float)(i + 1); break; }
    }
    if (sentinel == 0.0f && out_size != 8388608) sentinel = 6e7f;
    if (sentinel == 0.0f && ws_size < WS_MIN) sentinel = 1e8f + (float)ws_size;
    if (sentinel != 0.0f) {
        k_sentinel<<<1, 1, 0, stream>>>((float*)d_out, sentinel);
        return;
    }

    const float* x     = (const float*)d_in[0];
    const float* pair  = (const float*)d_in[1];
    const float* Wq    = (const float*)d_in[2];
    const float* Wkv   = (const float*)d_in[3];
    const float* Wout  = (const float*)d_in[4];
    const float* b_out = (const float*)d_in[5];
    const float* ln_g  = (const float*)d_in[6];
    const float* ln_b  = (const float*)d_in[7];
    const float* Wpair = (const float*)d_in[8];
    const float* Wq_sw = (const float*)d_in[9];
    const float* bq_sw = (const float*)d_in[10];
    const float* Wk_sw = (const float*)d_in[11];
    const float* bk_sw = (const float*)d_in[12];

    char* w = (char*)d_ws;
    float* dots = (float*)(w);
    float* sw   = (float*)(w + 1048576ULL);
    float* qsw  = (float*)(w + 1310720ULL);
    bf16*  q_h  = (bf16*)(w + 1572864ULL);
    bf16*  k_h  = (bf16*)(w + 5767168ULL);
    bf16*  om   = (bf16*)d_out;

    k_qsw<<<dim3(512), 128, 0, stream>>>(x, Wq_sw, bq_sw, qsw);

    if (ws_size >= WS_BIG) {
        bf16*  v_h = (bf16*)(w + 9961472ULL);
        float* pbh = (float*)(w + 14155776ULL);

        k_pb_all<<<dim3(65536), 256, 0, stream>>>(pair, ln_g, ln_b, Wpair, pbh);

        for (int h = 0; h < H_; ++h) {
            k_sw_h  <<<dim3(256),    256, 0, stream>>>(x, Wk_sw, bk_sw, qsw, sw, h);
            k_wrow2 <<<dim3(512),    128, 0, stream>>>(sw);
            k_proj96<<<dim3(8192),   256, 0, stream>>>(x, Wq, Wkv, h, sw, q_h, k_h, v_h);
            k_dots_mfma<<<dim3(8, 8),256, 0, stream>>>(q_h, k_h, pbh + (size_t)h * NN_, dots);
            k_smax  <<<dim3(512),    256, 0, stream>>>(dots);
            k_av_h  <<<dim3(8, 128), 256, 0, stream>>>(dots, v_h, om, h);
        }
    } else {
        bf16* v_h = k_h;   // alias (k dead after k_dots_mfma)
        for (int h = 0; h < H_; ++h) {
            k_pb_h  <<<dim3(65536),  256, 0, stream>>>(pair, ln_g, ln_b, Wpair, dots, h);
            k_sw_h  <<<dim3(256),    256, 0, stream>>>(x, Wk_sw, bk_sw, qsw, sw, h);
            k_wrow2 <<<dim3(512),    128, 0, stream>>>(sw);
            k_proj32<<<dim3(8192),   256, 0, stream>>>(x, Wq,  256, h * 32,       q_h, 0, sw);
            k_proj32<<<dim3(8192),   256, 0, stream>>>(x, Wkv, 512, h * 32,       k_h, 0, nullptr);
            k_dots_mfma<<<dim3(8, 8),256, 0, stream>>>(q_h, k_h, dots, dots);
            k_smax  <<<dim3(512),    256, 0, stream>>>(dots);
            k_proj32<<<dim3(8192),   256, 0, stream>>>(x, Wkv, 512, 256 + h * 32, v_h, 1, nullptr);
            k_av_h  <<<dim3(8, 128), 256, 0, stream>>>(dots, v_h, om, h);
        }
    }

    k_final<<<dim3(1024), 256, 0, stream>>>(om, Wout, b_out, (float*)d_out);
}

// Round 3
// 2047.210 us; speedup vs baseline: 1.4669x; 1.1139x over previous
//
#include <hip/hip_runtime.h>
#include <hip/hip_bf16.h>
#include <stdint.h>

#define R_ 128
#define N_ 512
#define DIM_ 128
#define H_ 8
#define DP_ 128
#define INNER_ 256
#define RD_ 4096   // R*DH
#define NN_ 262144 // N*N

typedef __hip_bfloat16 bf16;
typedef __attribute__((ext_vector_type(8))) short bfrag8;   // 8 bf16 (4 VGPRs)
typedef __attribute__((ext_vector_type(4))) float facc4;    // 4 fp32 acc

__device__ __forceinline__ float bf_lo(unsigned u) { return __uint_as_float(u << 16); }
__device__ __forceinline__ float bf_hi(unsigned u) { return __uint_as_float(u & 0xffff0000u); }

// round-to-nearest-even fp32 -> bf16 (as short), and back
__device__ __forceinline__ short bf_round(float x) {
    unsigned u = __float_as_uint(x);
    unsigned r = (u + 0x7fffu + ((u >> 16) & 1u)) >> 16;
    return (short)r;
}
__device__ __forceinline__ float bf_tof(short s) {
    return __uint_as_float(((unsigned)(unsigned short)s) << 16);
}

// ---------------------------------------------------------------------------
// Sentinel writer (interface diagnostics via absmax channel)
// ---------------------------------------------------------------------------
__global__ void k_sentinel(float* out, float v) { out[0] = v; }

// ---------------------------------------------------------------------------
// q_sw = x[0] @ Wq_sw + bq_sw  -> qsw [N][128] fp32   (once)
// ---------------------------------------------------------------------------
__global__ __launch_bounds__(128) void k_qsw(
    const float* __restrict__ x, const float* __restrict__ Wq_sw,
    const float* __restrict__ bq_sw, float* __restrict__ qsw)
{
    __shared__ float xr[128];
    const int n = blockIdx.x, t = threadIdx.x;
    xr[t] = x[(size_t)n * DIM_ + t];   // row r=0
    __syncthreads();
    float acc = bq_sw[t];
    for (int c = 0; c < 128; ++c) acc += xr[c] * Wq_sw[c * 128 + t];
    qsw[n * 128 + t] = acc;
}

// ---------------------------------------------------------------------------
// Prep for k_pb_mfma (runs once, 1 block):
//  WgT_hi/lo[16][128] bf16 split of (ln_g[c]*Wpair[c][h]) transposed,
//  col 8 = ones (Sigma v), cols 9..15 = 0.  G[8], B[8] per-head constants.
// ---------------------------------------------------------------------------
__global__ __launch_bounds__(128) void k_prep(
    const float* __restrict__ ln_g, const float* __restrict__ ln_b,
    const float* __restrict__ Wpair,
    short* __restrict__ wgt_hi, short* __restrict__ wgt_lo,
    float* __restrict__ G, float* __restrict__ B)
{
    const int c = threadIdx.x;
    float g = ln_g[c];
#pragma unroll
    for (int h = 0; h < 8; ++h) {
        float wg = g * Wpair[c * 8 + h];
        short hi = bf_round(wg);
        wgt_hi[h * 128 + c] = hi;
        wgt_lo[h * 128 + c] = bf_round(wg - bf_tof(hi));
    }
    wgt_hi[8 * 128 + c] = bf_round(1.0f);   // ones column -> Sigma v
    wgt_lo[8 * 128 + c] = 0;
#pragma unroll
    for (int h = 9; h < 16; ++h) { wgt_hi[h * 128 + c] = 0; wgt_lo[h * 128 + c] = 0; }
    __syncthreads();
    if (c < 8) {
        float Gs = 0.0f, Bs = 0.0f;
        for (int k = 0; k < 128; ++k) {
            Gs += ln_g[k] * Wpair[k * 8 + c];
            Bs += ln_b[k] * Wpair[k * 8 + c];
        }
        G[c] = Gs; B[c] = Bs;
    }
}

// ---------------------------------------------------------------------------
// Pair-bias via MFMA (once, all heads): for each pb row (i,j):
//   S_h = Sigma_c v_c*(g_c W_ch)  (bf16x3 split MFMA, fp32-quality)
//   Sigma v from ones-col (col 8); Sigma v^2 in-lane + 2 shuffles.
//   pbh[h][i*N+j] = rs*S_h - rs*mean*G_h + B_h
// Block: 256 thr / 4 waves, 64 pb-rows; wave = 16 rows (one 16x16 MFMA tile).
// ---------------------------------------------------------------------------
__global__ __launch_bounds__(256) void k_pb_mfma(
    const float* __restrict__ pb,
    const short* __restrict__ wgt_hi, const short* __restrict__ wgt_lo,
    const float* __restrict__ G, const float* __restrict__ B,
    float* __restrict__ pbh)
{
    __shared__ float ssum[64], svv[64];
    const int tid = threadIdx.x;
    const int wave = tid >> 6, lane = tid & 63;
    const int lr = lane & 15, lk = (lane >> 4) * 8;
    const int row0 = blockIdx.x * 64 + wave * 16;   // global pb-row base (this wave)
    const float* ap = pb + (size_t)(row0 + lr) * DP_ + lk;

    facc4 acc = {};
    float vv = 0.0f;
#pragma unroll
    for (int ks = 0; ks < 4; ++ks) {
        float4 u0 = *(const float4*)(ap + ks * 32);
        float4 u1 = *(const float4*)(ap + ks * 32 + 4);
        float v[8] = {u0.x, u0.y, u0.z, u0.w, u1.x, u1.y, u1.z, u1.w};
        bfrag8 ahi, alo;
#pragma unroll
        for (int i = 0; i < 8; ++i) {
            short hi = bf_round(v[i]);
            ahi[i] = hi;
            alo[i] = bf_round(v[i] - bf_tof(hi));
            vv += v[i] * v[i];
        }
        bfrag8 bhi = *(const bfrag8*)(wgt_hi + lr * 128 + lk + ks * 32);
        bfrag8 blo = *(const bfrag8*)(wgt_lo + lr * 128 + lk + ks * 32);
        acc = __builtin_amdgcn_mfma_f32_16x16x32_bf16(ahi, bhi, acc, 0, 0, 0);
        acc = __builtin_amdgcn_mfma_f32_16x16x32_bf16(alo, bhi, acc, 0, 0, 0);
        acc = __builtin_amdgcn_mfma_f32_16x16x32_bf16(ahi, blo, acc, 0, 0, 0);
    }
    // Sigma v^2: 4 lanes per row (l, l^16, l^32, l^48) hold channel quarters
    vv += __shfl_xor(vv, 16);
    vv += __shfl_xor(vv, 32);
    if (lane < 16) svv[wave * 16 + lr] = vv;
    // Sigma v lives in C col 8 (lanes with lr==8), rows (lane>>4)*4 + t
    const int crow = (lane >> 4) * 4;
    if (lr == 8) {
#pragma unroll
        for (int t = 0; t < 4; ++t) ssum[wave * 16 + crow + t] = acc[t];
    }
    __syncthreads();
    if (lr < 8) {
        const float Gh = G[lr], Bh = B[lr];
#pragma unroll
        for (int t = 0; t < 4; ++t) {
            int r16 = crow + t;
            float sv = ssum[wave * 16 + r16];
            float s2 = svv[wave * 16 + r16];
            float mean = sv * (1.0f / 128.0f);
            float var = s2 * (1.0f / 128.0f) - mean * mean;
            float rs = rsqrtf(var + 1e-5f);
            float p = rs * acc[t] - rs * mean * Gh + Bh;
            pbh[(size_t)lr * NN_ + (size_t)(row0 + r16)] = p;
        }
    }
}

// ---------------------------------------------------------------------------
// FALLBACK: per-head pair-bias LayerNorm + Wpair column h -> dots prefill
// ---------------------------------------------------------------------------
__global__ __launch_bounds__(256) void k_pb_h(
    const float* __restrict__ pb, const float* __restrict__ ln_g,
    const float* __restrict__ ln_b, const float* __restrict__ Wpair,
    float* __restrict__ dots, int h)
{
    __shared__ float sg[128], sb[128], wp[128];
    const int tid = threadIdx.x;
    if (tid < 128) { sg[tid] = ln_g[tid]; sb[tid] = ln_b[tid]; wp[tid] = Wpair[tid * 8 + h]; }
    __syncthreads();
    const int wave = tid >> 6, lane = tid & 63;
    const int flat = blockIdx.x * 4 + wave;    // i*N + j
    const float* pp = pb + (size_t)flat * DP_;
    float v0 = pp[lane], v1 = pp[lane + 64];
    float s = v0 + v1, ss = v0 * v0 + v1 * v1;
#pragma unroll
    for (int off = 32; off > 0; off >>= 1) {
        s  += __shfl_xor(s, off);
        ss += __shfl_xor(ss, off);
    }
    float mean = s * (1.0f / 128.0f);
    float var = ss * (1.0f / 128.0f) - mean * mean;
    float rs = rsqrtf(var + 1e-5f);
    float y0 = (v0 - mean) * rs * sg[lane] + sb[lane];
    float y1 = (v1 - mean) * rs * sg[lane + 64] + sb[lane + 64];
    float part = y0 * wp[lane] + y1 * wp[lane + 64];
#pragma unroll
    for (int off = 32; off > 0; off >>= 1) part += __shfl_xor(part, off);
    if (lane == 0) dots[flat] = part;
}

// ---------------------------------------------------------------------------
// Per head: sw[n][r] = dot16(qsw[n,h,:], x[r,n,:]@Wksw[:,h*16:]+b) * 0.25
// ---------------------------------------------------------------------------
__global__ __launch_bounds__(256) void k_sw_h(
    const float* __restrict__ x, const float* __restrict__ Wksw,
    const float* __restrict__ bksw, const float* __restrict__ qsw,
    float* __restrict__ sw, int h)
{
    const int idx = blockIdx.x * 256 + threadIdx.x;   // [0, 65536)
    const int n = idx >> 7, r = idx & 127;
    float acc[16];
#pragma unroll
    for (int d = 0; d < 16; ++d) acc[d] = bksw[h * 16 + d];
    const float* xr = x + (size_t)(r * N_ + n) * DIM_;
    for (int k = 0; k < 128; ++k) {
        float xv = xr[k];
        const float* wr = Wksw + k * 128 + h * 16;
#pragma unroll
        for (int d = 0; d < 16; ++d) acc[d] += xv * wr[d];
    }
    const float* qp = qsw + n * 128 + h * 16;
    float s = 0.0f;
#pragma unroll
    for (int d = 0; d < 16; ++d) s += acc[d] * qp[d];
    sw[n * 128 + r] = s * 0.25f;   // / sqrt(16 + 1e-8)
}

// ---------------------------------------------------------------------------
// softmax over r, in place on sw [N][R]
// ---------------------------------------------------------------------------
__global__ __launch_bounds__(128) void k_wrow2(float* __restrict__ sw)
{
    __shared__ float red[2];
    const int n = blockIdx.x, r = threadIdx.x;
    float s = sw[n * 128 + r];
    float m = s;
#pragma unroll
    for (int off = 32; off > 0; off >>= 1) m = fmaxf(m, __shfl_xor(m, off));
    if ((r & 63) == 0) red[r >> 6] = m;
    __syncthreads();
    m = fmaxf(red[0], red[1]);
    float e = __expf(s - m);
    float sum = e;
#pragma unroll
    for (int off = 32; off > 0; off >>= 1) sum += __shfl_xor(sum, off);
    __syncthreads();
    if ((r & 63) == 0) red[r >> 6] = sum;
    __syncthreads();
    sum = red[0] + red[1];
    sw[n * 128 + r] = e / sum;
}

// ---------------------------------------------------------------------------
// Merged per-head projection: q, k, v in ONE x pass.
//   q -> [(n*128+r)*32+d] bf16 (scaled by wrow)
//   k -> [(n*128+r)*32+d] bf16
//   v -> TRANSPOSED [(r*32+d)*512+n] bf16  (B-operand layout for k_av_mfma)
// ---------------------------------------------------------------------------
__global__ __launch_bounds__(256) void k_proj96(
    const float* __restrict__ x, const float* __restrict__ Wq,
    const float* __restrict__ Wkv, int h, const float* __restrict__ rowW,
    bf16* __restrict__ qo, bf16* __restrict__ ko, bf16* __restrict__ vo)
{
    __shared__ float xs[8][128];
    const int tid = threadIdx.x;
    const int row0 = blockIdx.x * 8;
#pragma unroll
    for (int l = 0; l < 4; ++l) {
        int idx = l * 256 + tid;
        int m = idx >> 7, k = idx & 127;
        xs[m][k] = x[(size_t)(row0 + m) * DIM_ + k];
    }
    __syncthreads();
    const int m = tid >> 5, d = tid & 31;
    const float* wq = Wq  + h * 32 + d;         // stride 256
    const float* wk = Wkv + h * 32 + d;         // stride 512
    const float* wv = Wkv + 256 + h * 32 + d;   // stride 512
    float aq = 0.0f, ak = 0.0f, av = 0.0f;
    for (int k = 0; k < 128; ++k) {
        float xv = xs[m][k];
        aq += xv * wq[k * 256];
        ak += xv * wk[k * 512];
        av += xv * wv[k * 512];
    }
    const int rowg = row0 + m;
    const int r = rowg >> 9, n = rowg & (N_ - 1);
    aq *= rowW[n * 128 + r];
    qo[((size_t)n * 128 + r) * 32 + d] = __float2bfloat16(aq);
    ko[((size_t)n * 128 + r) * 32 + d] = __float2bfloat16(ak);
    vo[((size_t)r * 32 + d) * 512 + n] = __float2bfloat16(av);
}

// ---------------------------------------------------------------------------
// FALLBACK: single 32-col projection per head (old v layout for k_av_h)
// ---------------------------------------------------------------------------
__global__ __launch_bounds__(256) void k_proj32(
    const float* __restrict__ x, const float* __restrict__ W,
    int ldw, int col0, bf16* __restrict__ out, int mode,
    const float* __restrict__ rowW)
{
    __shared__ float xs[8][128];
    const int tid = threadIdx.x;
    const int row0 = blockIdx.x * 8;
#pragma unroll
    for (int l = 0; l < 4; ++l) {
        int idx = l * 256 + tid;
        int m = idx >> 7, k = idx & 127;
        xs[m][k] = x[(size_t)(row0 + m) * DIM_ + k];
    }
    __syncthreads();
    const int m = tid >> 5, d = tid & 31;
    float acc = 0.0f;
    for (int k = 0; k < 128; ++k) acc += xs[m][k] * W[k * ldw + col0 + d];
    const int rowg = row0 + m;
    const int r = rowg >> 9, n = rowg & (N_ - 1);
    if (rowW) acc *= rowW[n * 128 + r];
    size_t o = (mode == 0) ? ((size_t)n * 128 + r) * 32 + d
                           : ((size_t)r * 512 + n) * 32 + d;
    out[o] = __float2bfloat16(acc);
}

// ---------------------------------------------------------------------------
// Per head (MFMA): dots[i][j] = base[i][j] + scale * sum_rd q[i][rd]*k[j][rd]
// ---------------------------------------------------------------------------
__global__ __launch_bounds__(256) void k_dots_mfma(
    const bf16* __restrict__ q_h, const bf16* __restrict__ k_h,
    const float* base, float* dots)
{
    const int tid  = threadIdx.x;
    const int wave = tid >> 6, lane = tid & 63;
    const int i0 = blockIdx.y * 64 + (wave >> 1) * 32;
    const int j0 = blockIdx.x * 64 + (wave & 1) * 32;
    const int lr = lane & 15;
    const int lk = (lane >> 4) * 8;

    const bf16* a0p = q_h + (((size_t)(i0 + lr))      << 12) + lk;
    const bf16* a1p = q_h + (((size_t)(i0 + 16 + lr)) << 12) + lk;
    const bf16* b0p = k_h + (((size_t)(j0 + lr))      << 12) + lk;
    const bf16* b1p = k_h + (((size_t)(j0 + 16 + lr)) << 12) + lk;

    facc4 acc00 = {}, acc01 = {}, acc10 = {}, acc11 = {};

#pragma unroll 4
    for (int k = 0; k < RD_; k += 32) {
        bfrag8 a0 = *(const bfrag8*)(a0p + k);
        bfrag8 a1 = *(const bfrag8*)(a1p + k);
        bfrag8 b0 = *(const bfrag8*)(b0p + k);
        bfrag8 b1 = *(const bfrag8*)(b1p + k);
        acc00 = __builtin_amdgcn_mfma_f32_16x16x32_bf16(a0, b0, acc00, 0, 0, 0);
        acc01 = __builtin_amdgcn_mfma_f32_16x16x32_bf16(a0, b1, acc01, 0, 0, 0);
        acc10 = __builtin_amdgcn_mfma_f32_16x16x32_bf16(a1, b0, acc10, 0, 0, 0);
        acc11 = __builtin_amdgcn_mfma_f32_16x16x32_bf16(a1, b1, acc11, 0, 0, 0);
    }

    const float scale = 0.17677669529663689f;   // 32^-0.5
    const int dr = (lane >> 4) * 4, dc = lane & 15;
#pragma unroll
    for (int t = 0; t < 4; ++t) {
        size_t i00 = (size_t)(i0 +      dr + t) * N_;
        size_t i16 = (size_t)(i0 + 16 + dr + t) * N_;
        dots[i00 + j0 +      dc] = base[i00 + j0 +      dc] + acc00[t] * scale;
        dots[i00 + j0 + 16 + dc] = base[i00 + j0 + 16 + dc] + acc01[t] * scale;
        dots[i16 + j0 +      dc] = base[i16 + j0 +      dc] + acc10[t] * scale;
        dots[i16 + j0 + 16 + dc] = base[i16 + j0 + 16 + dc] + acc11[t] * scale;
    }
}

// ---------------------------------------------------------------------------
// FALLBACK: row softmax over j, fp32 in place on dots [N][N]
// ---------------------------------------------------------------------------
__global__ __launch_bounds__(256) void k_smax(float* __restrict__ dots)
{
    __shared__ float red[4];
    const int i = blockIdx.x;
    const int t = threadIdx.x;
    float* p = dots + (size_t)i * N_;
    float a = p[t], b = p[t + 256];
    float m = fmaxf(a, b);
#pragma unroll
    for (int off = 32; off > 0; off >>= 1) m = fmaxf(m, __shfl_xor(m, off));
    if ((t & 63) == 0) red[t >> 6] = m;
    __syncthreads();
    m = fmaxf(fmaxf(red[0], red[1]), fmaxf(red[2], red[3]));
    float e0 = __expf(a - m), e1 = __expf(b - m);
    float s = e0 + e1;
#pragma unroll
    for (int off = 32; off > 0; off >>= 1) s += __shfl_xor(s, off);
    __syncthreads();
    if ((t & 63) == 0) red[t >> 6] = s;
    __syncthreads();
    s = red[0] + red[1] + red[2] + red[3];
    float inv = 1.0f / s;
    p[t] = e0 * inv;
    p[t + 256] = e1 * inv;
}

// ---------------------------------------------------------------------------
// row softmax -> SPLIT bf16 probs (hi at attn[0..NN), lo at attn[NN..2NN)),
// written into the dead pbh[h] plane. dots left unchanged (pre-softmax).
// ---------------------------------------------------------------------------
__global__ __launch_bounds__(256) void k_smax2(
    const float* __restrict__ dots, short* __restrict__ attn)
{
    __shared__ float red[4];
    const int i = blockIdx.x;
    const int t = threadIdx.x;
    const float* p = dots + (size_t)i * N_;
    float a = p[t], b = p[t + 256];
    float m = fmaxf(a, b);
#pragma unroll
    for (int off = 32; off > 0; off >>= 1) m = fmaxf(m, __shfl_xor(m, off));
    if ((t & 63) == 0) red[t >> 6] = m;
    __syncthreads();
    m = fmaxf(fmaxf(red[0], red[1]), fmaxf(red[2], red[3]));
    float e0 = __expf(a - m), e1 = __expf(b - m);
    float s = e0 + e1;
#pragma unroll
    for (int off = 32; off > 0; off >>= 1) s += __shfl_xor(s, off);
    __syncthreads();
    if ((t & 63) == 0) red[t >> 6] = s;
    __syncthreads();
    s = red[0] + red[1] + red[2] + red[3];
    float inv = 1.0f / s;
    float p0 = e0 * inv, p1 = e1 * inv;
    short h0 = bf_round(p0), h1 = bf_round(p1);
    attn[(size_t)i * N_ + t]             = h0;
    attn[(size_t)i * N_ + t + 256]       = h1;
    attn[NN_ + (size_t)i * N_ + t]       = bf_round(p0 - bf_tof(h0));
    attn[NN_ + (size_t)i * N_ + t + 256] = bf_round(p1 - bf_tof(h1));
}

// ---------------------------------------------------------------------------
// Per head (MFMA): om[r][i][h*32+d] = sum_j P[i][j] * v[r][j][d]
// P = attn_hi + attn_lo (split bf16, fp32-quality); vt layout [r][d][j].
// Grid (8 i-blocks, 128 r); 4 waves; wave = 16 i x 32 d; K=j=512.
// ---------------------------------------------------------------------------
__global__ __launch_bounds__(256) void k_av_mfma(
    const short* __restrict__ attn, const bf16* __restrict__ vt,
    bf16* __restrict__ om, int h)
{
    const int tid = threadIdx.x;
    const int wave = tid >> 6, lane = tid & 63;
    const int r = blockIdx.y;
    const int i0 = blockIdx.x * 64 + wave * 16;
    const int lr = lane & 15, lk = (lane >> 4) * 8;

    const short* pah = attn + (size_t)(i0 + lr) * N_ + lk;
    const short* pal = pah + NN_;
    const short* pb0 = (const short*)vt + ((size_t)r * 32 + lr) * N_ + lk;
    const short* pb1 = pb0 + 16 * N_;

    facc4 acc0 = {}, acc1 = {};
#pragma unroll 4
    for (int k = 0; k < N_; k += 32) {
        bfrag8 ah = *(const bfrag8*)(pah + k);
        bfrag8 al = *(const bfrag8*)(pal + k);
        bfrag8 b0 = *(const bfrag8*)(pb0 + k);
        bfrag8 b1 = *(const bfrag8*)(pb1 + k);
        acc0 = __builtin_amdgcn_mfma_f32_16x16x32_bf16(ah, b0, acc0, 0, 0, 0);
        acc0 = __builtin_amdgcn_mfma_f32_16x16x32_bf16(al, b0, acc0, 0, 0, 0);
        acc1 = __builtin_amdgcn_mfma_f32_16x16x32_bf16(ah, b1, acc1, 0, 0, 0);
        acc1 = __builtin_amdgcn_mfma_f32_16x16x32_bf16(al, b1, acc1, 0, 0, 0);
    }
    const int crow = (lane >> 4) * 4, ccol = lane & 15;
#pragma unroll
    for (int t = 0; t < 4; ++t) {
        size_t ob = ((size_t)r * N_ + i0 + crow + t) * INNER_ + h * 32;
        om[ob + ccol]      = __float2bfloat16(acc0[t]);
        om[ob + 16 + ccol] = __float2bfloat16(acc1[t]);
    }
}

// ---------------------------------------------------------------------------
// FALLBACK: per-head AV, fp32 VALU, old v layout [r][j][d]
// ---------------------------------------------------------------------------
__global__ __launch_bounds__(256) void k_av_h(
    const float* __restrict__ attn, const bf16* __restrict__ v_h,
    bf16* __restrict__ om, int h)
{
    __shared__ float as[64][66];
    __shared__ float vs[64][34];
    const int tid = threadIdx.x;
    const int it = blockIdx.x, r = blockIdx.y;
    const int i0 = it * 64;
    const int ti = tid >> 4, td = tid & 15;
    float acc[4][2] = {};

    for (int j0 = 0; j0 < N_; j0 += 64) {
#pragma unroll
        for (int l = 0; l < 4; ++l) {
            int idx = l * 256 + tid;
            int i = idx >> 4, j4 = idx & 15;
            float4 u = *(const float4*)(attn + (size_t)(i0 + i) * N_ + j0 + j4 * 4);
            float* d = &as[i][j4 * 4];
            d[0] = u.x; d[1] = u.y; d[2] = u.z; d[3] = u.w;
        }
        {
            int j = tid >> 2, ck = tid & 3;
            uint4 u = *(const uint4*)(v_h + ((size_t)r * N_ + j0 + j) * 32 + ck * 8);
            float* d = &vs[j][ck * 8];
            d[0] = bf_lo(u.x); d[1] = bf_hi(u.x); d[2] = bf_lo(u.y); d[3] = bf_hi(u.y);
            d[4] = bf_lo(u.z); d[5] = bf_hi(u.z); d[6] = bf_lo(u.w); d[7] = bf_hi(u.w);
        }
        __syncthreads();
#pragma unroll 8
        for (int jj = 0; jj < 64; jj += 2) {
            float2 b0 = *(const float2*)&vs[jj][td * 2];
            float2 b1 = *(const float2*)&vs[jj + 1][td * 2];
#pragma unroll
            for (int i = 0; i < 4; ++i) {
                float2 a = *(const float2*)&as[ti * 4 + i][jj];
                acc[i][0] += a.x * b0.x + a.y * b1.x;
                acc[i][1] += a.x * b0.y + a.y * b1.y;
            }
        }
        __syncthreads();
    }
#pragma unroll
    for (int ii = 0; ii < 4; ++ii) {
        bf16* op = om + ((size_t)r * N_ + i0 + ti * 4 + ii) * INNER_ + h * 32 + td * 2;
        op[0] = __float2bfloat16(acc[ii][0]);
        op[1] = __float2bfloat16(acc[ii][1]);
    }
}

// ---------------------------------------------------------------------------
// out = om @ Wout + b_out, IN PLACE on d_out (om bf16 -> out fp32).
// ---------------------------------------------------------------------------
__global__ __launch_bounds__(256) void k_final(
    const bf16* om, const float* __restrict__ Wout,
    const float* __restrict__ b_out, float* out)
{
    __shared__ float as[64][68];
    __shared__ float ws[64][132];
    const int tid = threadIdx.x;
    const int row0 = blockIdx.x * 64;
    const int tm = tid >> 5, tc = tid & 31;
    float acc[8][4] = {};

    for (int k0 = 0; k0 < INNER_; k0 += 64) {
#pragma unroll
        for (int l = 0; l < 2; ++l) {
            int idx = l * 256 + tid;
            int m = idx >> 3, ck = idx & 7;
            uint4 u = *(const uint4*)(om + (size_t)(row0 + m) * INNER_ + k0 + ck * 8);
            float* d = &as[m][ck * 8];
            d[0] = bf_lo(u.x); d[1] = bf_hi(u.x); d[2] = bf_lo(u.y); d[3] = bf_hi(u.y);
            d[4] = bf_lo(u.z); d[5] = bf_hi(u.z); d[6] = bf_lo(u.w); d[7] = bf_hi(u.w);
        }
#pragma unroll
        for (int l = 0; l < 8; ++l) {
            int idx = l * 256 + tid;
            int kk = idx >> 5, c4 = idx & 31;
            float4 u = *(const float4*)(Wout + (size_t)(k0 + kk) * DIM_ + c4 * 4);
            float* d = &ws[kk][c4 * 4];
            d[0] = u.x; d[1] = u.y; d[2] = u.z; d[3] = u.w;
        }
        __syncthreads();
        for (int kk = 0; kk < 64; kk += 2) {
            float4 b0 = *(const float4*)&ws[kk][tc * 4];
            float4 b1 = *(const float4*)&ws[kk + 1][tc * 4];
#pragma unroll
            for (int i = 0; i < 8; ++i) {
                float2 a = *(const float2*)&as[tm * 8 + i][kk];
                acc[i][0] += a.x * b0.x + a.y * b1.x;
                acc[i][1] += a.x * b0.y + a.y * b1.y;
                acc[i][2] += a.x * b0.z + a.y * b1.z;
                acc[i][3] += a.x * b0.w + a.y * b1.w;
            }
        }
        __syncthreads();
    }
#pragma unroll
    for (int ii = 0; ii < 8; ++ii) {
        int rowg = row0 + tm * 8 + ii;
#pragma unroll
        for (int jj = 0; jj < 4; ++jj) {
            int cg = tc * 4 + jj;
            out[(size_t)rowg * DIM_ + cg] = acc[ii][jj] + b_out[cg];
        }
    }
}

// ---------------------------------------------------------------------------
// Workspace arena (high-water 22,544,384 B, unchanged from round 2):
//   [0        ..  1,048,576)  dots [N][N] fp32; first 8.3 KB doubles as
//                             prep consts (WgT_hi/lo, G, B) until 1st dots
//   [1,048,576..  1,310,720)  sw   [N][R] fp32 (-> wrow in place)
//   [1,310,720..  1,572,864)  qsw  [N][128] fp32
//   [1,572,864..  5,767,168)  q_h  [N][R][32] bf16 (pre-scaled by wrow)
//   [5,767,168..  9,961,472)  k_h  [N][R][32] bf16
//   [9,961,472.. 14,155,776)  v_h  TRANSPOSED [R][32][N] bf16
//   [14,155,776..22,544,384)  pbh  [8][N][N] fp32; plane h is recycled as
//                             split-bf16 attn (hi|lo) after k_dots_mfma(h)
// om (bf16, 33.55 MB) lives in d_out; k_final converts to fp32 in place.
// ---------------------------------------------------------------------------
extern "C" void kernel_launch(void* const* d_in, const int* in_sizes, int n_in,
                              void* d_out, int out_size, void* d_ws, size_t ws_size,
                              hipStream_t stream)
{
    static const int exp_sizes[13] = {8388608, 33554432, 32768, 65536, 32768,
                                      128, 128, 128, 1024, 16384, 128, 16384, 128};
    const size_t WS_MIN = 9961472ULL;
    const size_t WS_BIG = 22544384ULL;
    float sentinel = 0.0f;
    if (n_in != 13) sentinel = 5e7f;
    else {
        for (int i = 0; i < 13; ++i)
            if (in_sizes[i] != exp_sizes[i]) { sentinel = 1e6f * (float)(i + 1); break; }
    }
    if (sentinel == 0.0f && out_size != 8388608) sentinel = 6e7f;
    if (sentinel == 0.0f && ws_size < WS_MIN) sentinel = 1e8f + (float)ws_size;
    if (sentinel != 0.0f) {
        k_sentinel<<<1, 1, 0, stream>>>((float*)d_out, sentinel);
        return;
    }

    const float* x     = (const float*)d_in[0];
    const float* pair  = (const float*)d_in[1];
    const float* Wq    = (const float*)d_in[2];
    const float* Wkv   = (const float*)d_in[3];
    const float* Wout  = (const float*)d_in[4];
    const float* b_out = (const float*)d_in[5];
    const float* ln_g  = (const float*)d_in[6];
    const float* ln_b  = (const float*)d_in[7];
    const float* Wpair = (const float*)d_in[8];
    const float* Wq_sw = (const float*)d_in[9];
    const float* bq_sw = (const float*)d_in[10];
    const float* Wk_sw = (const float*)d_in[11];
    const float* bk_sw = (const float*)d_in[12];

    char* w = (char*)d_ws;
    float* dots = (float*)(w);
    float* sw   = (float*)(w + 1048576ULL);
    float* qsw  = (float*)(w + 1310720ULL);
    bf16*  q_h  = (bf16*)(w + 1572864ULL);
    bf16*  k_h  = (bf16*)(w + 5767168ULL);
    bf16*  om   = (bf16*)d_out;

    k_qsw<<<dim3(512), 128, 0, stream>>>(x, Wq_sw, bq_sw, qsw);

    if (ws_size >= WS_BIG) {
        bf16*  v_h = (bf16*)(w + 9961472ULL);
        float* pbh = (float*)(w + 14155776ULL);

        // prep consts live in the dots buffer (dead until first k_dots_mfma)
        short* wgt_hi = (short*)dots;           // 4096 B
        short* wgt_lo = (short*)dots + 2048;    // 4096 B @ byte 4096
        float* Gc     = dots + 2048;            // byte 8192
        float* Bc     = dots + 2056;            // byte 8224

        k_prep   <<<dim3(1),     128, 0, stream>>>(ln_g, ln_b, Wpair, wgt_hi, wgt_lo, Gc, Bc);
        k_pb_mfma<<<dim3(4096),  256, 0, stream>>>(pair, wgt_hi, wgt_lo, Gc, Bc, pbh);

        for (int h = 0; h < H_; ++h) {
            short* attn = (short*)(pbh + (size_t)h * NN_);  // plane recycled after dots
            k_sw_h  <<<dim3(256),    256, 0, stream>>>(x, Wk_sw, bk_sw, qsw, sw, h);
            k_wrow2 <<<dim3(512),    128, 0, stream>>>(sw);
            k_proj96<<<dim3(8192),   256, 0, stream>>>(x, Wq, Wkv, h, sw, q_h, k_h, v_h);
            k_dots_mfma<<<dim3(8, 8),256, 0, stream>>>(q_h, k_h, pbh + (size_t)h * NN_, dots);
            k_smax2 <<<dim3(512),    256, 0, stream>>>(dots, attn);
            k_av_mfma<<<dim3(8, 128),256, 0, stream>>>(attn, v_h, om, h);
        }
    } else {
        bf16* v_h = k_h;   // alias (k dead after k_dots_mfma)
        for (int h = 0; h < H_; ++h) {
            k_pb_h  <<<dim3(65536),  256, 0, stream>>>(pair, ln_g, ln_b, Wpair, dots, h);
            k_sw_h  <<<dim3(256),    256, 0, stream>>>(x, Wk_sw, bk_sw, qsw, sw, h);
            k_wrow2 <<<dim3(512),    128, 0, stream>>>(sw);
            k_proj32<<<dim3(8192),   256, 0, stream>>>(x, Wq,  256, h * 32,       q_h, 0, sw);
            k_proj32<<<dim3(8192),   256, 0, stream>>>(x, Wkv, 512, h * 32,       k_h, 0, nullptr);
            k_dots_mfma<<<dim3(8, 8),256, 0, stream>>>(q_h, k_h, dots, dots);
            k_smax  <<<dim3(512),    256, 0, stream>>>(dots);
            k_proj32<<<dim3(8192),   256, 0, stream>>>(x, Wkv, 512, 256 + h * 32, v_h, 1, nullptr);
            k_av_h  <<<dim3(8, 128), 256, 0, stream>>>(dots, v_h, om, h);
        }
    }

    k_final<<<dim3(1024), 256, 0, stream>>>(om, Wout, b_out, (float*)d_out);
}

// Round 5
// 1402.831 us; speedup vs baseline: 2.1408x; 1.4593x over previous
//
#include <hip/hip_runtime.h>
#include <hip/hip_bf16.h>
#include <stdint.h>

#define R_ 128
#define N_ 512
#define DIM_ 128
#define H_ 8
#define DP_ 128
#define INNER_ 256
#define RD_ 4096   // R*DH
#define NN_ 262144 // N*N

typedef __hip_bfloat16 bf16;
typedef __attribute__((ext_vector_type(8))) short bfrag8;   // 8 bf16 (4 VGPRs)
typedef __attribute__((ext_vector_type(4))) float facc4;    // 4 fp32 acc

__device__ __forceinline__ float bf_lo(unsigned u) { return __uint_as_float(u << 16); }
__device__ __forceinline__ float bf_hi(unsigned u) { return __uint_as_float(u & 0xffff0000u); }

// round-to-nearest-even fp32 -> bf16 (as short), and back
__device__ __forceinline__ short bf_round(float x) {
    unsigned u = __float_as_uint(x);
    unsigned r = (u + 0x7fffu + ((u >> 16) & 1u)) >> 16;
    return (short)r;
}
__device__ __forceinline__ float bf_tof(short s) {
    return __uint_as_float(((unsigned)(unsigned short)s) << 16);
}

// ---------------------------------------------------------------------------
// Sentinel writer (interface diagnostics via absmax channel)
// ---------------------------------------------------------------------------
__global__ void k_sentinel(float* out, float v) { out[0] = v; }

// ---------------------------------------------------------------------------
// x (fp32) -> xbf (bf16), 8 elems/thread, once
// ---------------------------------------------------------------------------
__global__ __launch_bounds__(256) void k_xbf(
    const float* __restrict__ x, short* __restrict__ xbf)
{
    size_t i = ((size_t)blockIdx.x * 256 + threadIdx.x) * 8;
    float4 u0 = *(const float4*)(x + i);
    float4 u1 = *(const float4*)(x + i + 4);
    bfrag8 o;
    o[0] = bf_round(u0.x); o[1] = bf_round(u0.y);
    o[2] = bf_round(u0.z); o[3] = bf_round(u0.w);
    o[4] = bf_round(u1.x); o[5] = bf_round(u1.y);
    o[6] = bf_round(u1.z); o[7] = bf_round(u1.w);
    *(bfrag8*)(xbf + i) = o;
}

// ---------------------------------------------------------------------------
// Weight prep (once): transposed hi/lo bf16 splits.
//  wqkv[c=h*96+s][k], s<32: Wq col h*32+s; s<64: Wkv col h*32+s-32;
//                     else: Wkv col 256+h*32+s-64
//  wout[c][k] = Wout[k][c]   (128 x 256)
//  wksw[c][k] = Wk_sw[k][c]  (128 x 128)
// ---------------------------------------------------------------------------
__global__ __launch_bounds__(256) void k_prep_all(
    const float* __restrict__ Wq, const float* __restrict__ Wkv,
    const float* __restrict__ Wout, const float* __restrict__ Wksw,
    short* __restrict__ wqkv_hi, short* __restrict__ wqkv_lo,
    short* __restrict__ wo_hi, short* __restrict__ wo_lo,
    short* __restrict__ wk_hi, short* __restrict__ wk_lo)
{
    int id = blockIdx.x * 256 + threadIdx.x;
    if (id < 98304) {
        int c = id >> 7, k = id & 127;
        int h = c / 96, s = c - h * 96;
        float w = (s < 32) ? Wq[k * 256 + h * 32 + s]
                : (s < 64) ? Wkv[k * 512 + h * 32 + (s - 32)]
                           : Wkv[k * 512 + 256 + h * 32 + (s - 64)];
        short hi = bf_round(w);
        wqkv_hi[id] = hi; wqkv_lo[id] = bf_round(w - bf_tof(hi));
    } else if (id < 131072) {
        int id2 = id - 98304; int c = id2 >> 8, k = id2 & 255;
        float w = Wout[k * 128 + c];
        short hi = bf_round(w);
        wo_hi[id2] = hi; wo_lo[id2] = bf_round(w - bf_tof(hi));
    } else if (id < 147456) {
        int id3 = id - 131072; int c = id3 >> 7, k = id3 & 127;
        float w = Wksw[k * 128 + c];
        short hi = bf_round(w);
        wk_hi[id3] = hi; wk_lo[id3] = bf_round(w - bf_tof(hi));
    }
}

// ---------------------------------------------------------------------------
// q_sw = x[0] @ Wq_sw + bq_sw  -> qsw [N][128] fp32   (once)
// ---------------------------------------------------------------------------
__global__ __launch_bounds__(128) void k_qsw(
    const float* __restrict__ x, const float* __restrict__ Wq_sw,
    const float* __restrict__ bq_sw, float* __restrict__ qsw)
{
    __shared__ float xr[128];
    const int n = blockIdx.x, t = threadIdx.x;
    xr[t] = x[(size_t)n * DIM_ + t];   // row r=0
    __syncthreads();
    float acc = bq_sw[t];
    for (int c = 0; c < 128; ++c) acc += xr[c] * Wq_sw[c * 128 + t];
    qsw[n * 128 + t] = acc;
}

// ---------------------------------------------------------------------------
// Prep for k_pb_mfma (runs once, 1 block):
//  WgT_hi/lo[16][128] bf16 split of (ln_g[c]*Wpair[c][h]) transposed,
//  col 8 = ones (Sigma v), cols 9..15 = 0.  G[8], B[8] per-head constants.
// ---------------------------------------------------------------------------
__global__ __launch_bounds__(128) void k_prep(
    const float* __restrict__ ln_g, const float* __restrict__ ln_b,
    const float* __restrict__ Wpair,
    short* __restrict__ wgt_hi, short* __restrict__ wgt_lo,
    float* __restrict__ G, float* __restrict__ B)
{
    const int c = threadIdx.x;
    float g = ln_g[c];
#pragma unroll
    for (int h = 0; h < 8; ++h) {
        float wg = g * Wpair[c * 8 + h];
        short hi = bf_round(wg);
        wgt_hi[h * 128 + c] = hi;
        wgt_lo[h * 128 + c] = bf_round(wg - bf_tof(hi));
    }
    wgt_hi[8 * 128 + c] = bf_round(1.0f);   // ones column -> Sigma v
    wgt_lo[8 * 128 + c] = 0;
#pragma unroll
    for (int h = 9; h < 16; ++h) { wgt_hi[h * 128 + c] = 0; wgt_lo[h * 128 + c] = 0; }
    __syncthreads();
    if (c < 8) {
        float Gs = 0.0f, Bs = 0.0f;
        for (int k = 0; k < 128; ++k) {
            Gs += ln_g[k] * Wpair[k * 8 + c];
            Bs += ln_b[k] * Wpair[k * 8 + c];
        }
        G[c] = Gs; B[c] = Bs;
    }
}

// ---------------------------------------------------------------------------
// Pair-bias via MFMA (once, all heads) -> pbh [8][N][N] fp32
// ---------------------------------------------------------------------------
__global__ __launch_bounds__(256) void k_pb_mfma(
    const float* __restrict__ pb,
    const short* __restrict__ wgt_hi, const short* __restrict__ wgt_lo,
    const float* __restrict__ G, const float* __restrict__ B,
    float* __restrict__ pbh)
{
    __shared__ float ssum[64], svv[64];
    const int tid = threadIdx.x;
    const int wave = tid >> 6, lane = tid & 63;
    const int lr = lane & 15, lk = (lane >> 4) * 8;
    const int row0 = blockIdx.x * 64 + wave * 16;
    const float* ap = pb + (size_t)(row0 + lr) * DP_ + lk;

    facc4 acc = {};
    float vv = 0.0f;
#pragma unroll
    for (int ks = 0; ks < 4; ++ks) {
        float4 u0 = *(const float4*)(ap + ks * 32);
        float4 u1 = *(const float4*)(ap + ks * 32 + 4);
        float v[8] = {u0.x, u0.y, u0.z, u0.w, u1.x, u1.y, u1.z, u1.w};
        bfrag8 ahi, alo;
#pragma unroll
        for (int i = 0; i < 8; ++i) {
            short hi = bf_round(v[i]);
            ahi[i] = hi;
            alo[i] = bf_round(v[i] - bf_tof(hi));
            vv += v[i] * v[i];
        }
        bfrag8 bhi = *(const bfrag8*)(wgt_hi + lr * 128 + lk + ks * 32);
        bfrag8 blo = *(const bfrag8*)(wgt_lo + lr * 128 + lk + ks * 32);
        acc = __builtin_amdgcn_mfma_f32_16x16x32_bf16(ahi, bhi, acc, 0, 0, 0);
        acc = __builtin_amdgcn_mfma_f32_16x16x32_bf16(alo, bhi, acc, 0, 0, 0);
        acc = __builtin_amdgcn_mfma_f32_16x16x32_bf16(ahi, blo, acc, 0, 0, 0);
    }
    vv += __shfl_xor(vv, 16);
    vv += __shfl_xor(vv, 32);
    if (lane < 16) svv[wave * 16 + lr] = vv;
    const int crow = (lane >> 4) * 4;
    if (lr == 8) {
#pragma unroll
        for (int t = 0; t < 4; ++t) ssum[wave * 16 + crow + t] = acc[t];
    }
    __syncthreads();
    if (lr < 8) {
        const float Gh = G[lr], Bh = B[lr];
#pragma unroll
        for (int t = 0; t < 4; ++t) {
            int r16 = crow + t;
            float sv = ssum[wave * 16 + r16];
            float s2 = svv[wave * 16 + r16];
            float mean = sv * (1.0f / 128.0f);
            float var = s2 * (1.0f / 128.0f) - mean * mean;
            float rs = rsqrtf(var + 1e-5f);
            float p = rs * acc[t] - rs * mean * Gh + Bh;
            pbh[(size_t)lr * NN_ + (size_t)(row0 + r16)] = p;
        }
    }
}

// ---------------------------------------------------------------------------
// ksw GEMM + fused sw epilogue (once, all heads):
//  ksw[rowg] = xbf[rowg] @ Wk_sw + bk_sw  (MFMA, hi/lo weights)
//  sw_all[h][n][r] = 0.25 * dot16(qsw[n,h*16:], ksw[rowg,h*16:])
// Block: 64 rows (fixed r, 64 consecutive n), 4 waves, 8 col-tiles.
// ---------------------------------------------------------------------------
__global__ __launch_bounds__(256) void k_swk(
    const short* __restrict__ xbf, const short* __restrict__ wk_hi,
    const short* __restrict__ wk_lo, const float* __restrict__ bksw,
    const float* __restrict__ qsw, float* __restrict__ sw_all)
{
    __shared__ float ls[64][132];
    const int tid = threadIdx.x;
    const int wave = tid >> 6, lane = tid & 63;
    const int lr = lane & 15, lko = (lane >> 4) * 8;
    const int rowb = blockIdx.x * 64;
    const int r = blockIdx.x >> 3, n0 = (blockIdx.x & 7) * 64;
    const short* ap = xbf + (size_t)(rowb + wave * 16 + lr) * 128 + lko;

    facc4 f[8] = {};
#pragma unroll
    for (int ks = 0; ks < 4; ++ks) {
        bfrag8 a = *(const bfrag8*)(ap + ks * 32);
#pragma unroll
        for (int ct = 0; ct < 8; ++ct) {
            bfrag8 bh = *(const bfrag8*)(wk_hi + (ct * 16 + lr) * 128 + ks * 32 + lko);
            bfrag8 bl = *(const bfrag8*)(wk_lo + (ct * 16 + lr) * 128 + ks * 32 + lko);
            f[ct] = __builtin_amdgcn_mfma_f32_16x16x32_bf16(a, bh, f[ct], 0, 0, 0);
            f[ct] = __builtin_amdgcn_mfma_f32_16x16x32_bf16(a, bl, f[ct], 0, 0, 0);
        }
    }
    const int crow = (lane >> 4) * 4, ccol = lane & 15;
#pragma unroll
    for (int ct = 0; ct < 8; ++ct) {
        float bb = bksw[ct * 16 + ccol];
#pragma unroll
        for (int t = 0; t < 4; ++t)
            ls[wave * 16 + crow + t][ct * 16 + ccol] = f[ct][t] + bb;
    }
    __syncthreads();
#pragma unroll
    for (int l = 0; l < 2; ++l) {
        int id = l * 256 + tid;
        int row = id >> 3, h = id & 7;
        int n = n0 + row;
        const float* qp = qsw + n * 128 + h * 16;
        float s = 0.0f;
#pragma unroll
        for (int d = 0; d < 16; ++d) s += ls[row][h * 16 + d] * qp[d];
        sw_all[((size_t)h * 512 + n) * 128 + r] = s * 0.25f;
    }
}

// ---------------------------------------------------------------------------
// FALLBACK: per-head pair-bias LayerNorm + Wpair column h -> dots prefill
// ---------------------------------------------------------------------------
__global__ __launch_bounds__(256) void k_pb_h(
    const float* __restrict__ pb, const float* __restrict__ ln_g,
    const float* __restrict__ ln_b, const float* __restrict__ Wpair,
    float* __restrict__ dots, int h)
{
    __shared__ float sg[128], sb[128], wp[128];
    const int tid = threadIdx.x;
    if (tid < 128) { sg[tid] = ln_g[tid]; sb[tid] = ln_b[tid]; wp[tid] = Wpair[tid * 8 + h]; }
    __syncthreads();
    const int wave = tid >> 6, lane = tid & 63;
    const int flat = blockIdx.x * 4 + wave;
    const float* pp = pb + (size_t)flat * DP_;
    float v0 = pp[lane], v1 = pp[lane + 64];
    float s = v0 + v1, ss = v0 * v0 + v1 * v1;
#pragma unroll
    for (int off = 32; off > 0; off >>= 1) {
        s  += __shfl_xor(s, off);
        ss += __shfl_xor(ss, off);
    }
    float mean = s * (1.0f / 128.0f);
    float var = ss * (1.0f / 128.0f) - mean * mean;
    float rs = rsqrtf(var + 1e-5f);
    float y0 = (v0 - mean) * rs * sg[lane] + sb[lane];
    float y1 = (v1 - mean) * rs * sg[lane + 64] + sb[lane + 64];
    float part = y0 * wp[lane] + y1 * wp[lane + 64];
#pragma unroll
    for (int off = 32; off > 0; off >>= 1) part += __shfl_xor(part, off);
    if (lane == 0) dots[flat] = part;
}

// ---------------------------------------------------------------------------
// FALLBACK: per head sw
// ---------------------------------------------------------------------------
__global__ __launch_bounds__(256) void k_sw_h(
    const float* __restrict__ x, const float* __restrict__ Wksw,
    const float* __restrict__ bksw, const float* __restrict__ qsw,
    float* __restrict__ sw, int h)
{
    const int idx = blockIdx.x * 256 + threadIdx.x;
    const int n = idx >> 7, r = idx & 127;
    float acc[16];
#pragma unroll
    for (int d = 0; d < 16; ++d) acc[d] = bksw[h * 16 + d];
    const float* xr = x + (size_t)(r * N_ + n) * DIM_;
    for (int k = 0; k < 128; ++k) {
        float xv = xr[k];
        const float* wr = Wksw + k * 128 + h * 16;
#pragma unroll
        for (int d = 0; d < 16; ++d) acc[d] += xv * wr[d];
    }
    const float* qp = qsw + n * 128 + h * 16;
    float s = 0.0f;
#pragma unroll
    for (int d = 0; d < 16; ++d) s += acc[d] * qp[d];
    sw[n * 128 + r] = s * 0.25f;
}

// ---------------------------------------------------------------------------
// softmax over r, in place, one block per row of 128
// ---------------------------------------------------------------------------
__global__ __launch_bounds__(128) void k_wrow2(float* __restrict__ sw)
{
    __shared__ float red[2];
    const int n = blockIdx.x, r = threadIdx.x;
    float s = sw[n * 128 + r];
    float m = s;
#pragma unroll
    for (int off = 32; off > 0; off >>= 1) m = fmaxf(m, __shfl_xor(m, off));
    if ((r & 63) == 0) red[r >> 6] = m;
    __syncthreads();
    m = fmaxf(red[0], red[1]);
    float e = __expf(s - m);
    float sum = e;
#pragma unroll
    for (int off = 32; off > 0; off >>= 1) sum += __shfl_xor(sum, off);
    __syncthreads();
    if ((r & 63) == 0) red[r >> 6] = sum;
    __syncthreads();
    sum = red[0] + red[1];
    sw[n * 128 + r] = e / sum;
}

// ---------------------------------------------------------------------------
// Per-head q/k/v projection via MFMA from xbf (65536 x 96 x 128):
//  q (cols 0..31, wrow-scaled) -> [(n*128+r)*32+d] bf16
//  k (cols 32..63)             -> [(n*128+r)*32+d] bf16
//  v (cols 64..95)             -> TRANSPOSED [(r*32+d)*512+n] via LDS
// ---------------------------------------------------------------------------
__global__ __launch_bounds__(256) void k_proj_mfma(
    const short* __restrict__ xbf, const short* __restrict__ wt_hi,
    const short* __restrict__ wt_lo, int h, const float* __restrict__ wrow_h,
    bf16* __restrict__ qo, bf16* __restrict__ ko, short* __restrict__ vt)
{
    __shared__ short vs[64][36];
    const int tid = threadIdx.x;
    const int wave = tid >> 6, lane = tid & 63;
    const int lr = lane & 15, lko = (lane >> 4) * 8;
    const int rowb = blockIdx.x * 64;
    const int r = blockIdx.x >> 3, n0 = (blockIdx.x & 7) * 64;
    const short* ap = xbf + (size_t)(rowb + wave * 16 + lr) * 128 + lko;
    const short* bh_base = wt_hi + (size_t)h * 96 * 128;
    const short* bl_base = wt_lo + (size_t)h * 96 * 128;

    facc4 f[6] = {};
#pragma unroll
    for (int ks = 0; ks < 4; ++ks) {
        bfrag8 a = *(const bfrag8*)(ap + ks * 32);
#pragma unroll
        for (int ct = 0; ct < 6; ++ct) {
            bfrag8 bh = *(const bfrag8*)(bh_base + (ct * 16 + lr) * 128 + ks * 32 + lko);
            bfrag8 bl = *(const bfrag8*)(bl_base + (ct * 16 + lr) * 128 + ks * 32 + lko);
            f[ct] = __builtin_amdgcn_mfma_f32_16x16x32_bf16(a, bh, f[ct], 0, 0, 0);
            f[ct] = __builtin_amdgcn_mfma_f32_16x16x32_bf16(a, bl, f[ct], 0, 0, 0);
        }
    }
    const int crow = (lane >> 4) * 4, ccol = lane & 15;
#pragma unroll
    for (int t = 0; t < 4; ++t) {
        int row = wave * 16 + crow + t;
        int n = n0 + row;
        float wv = wrow_h[n * 128 + r];
        size_t qk = ((size_t)n * 128 + r) * 32;
        qo[qk + ccol]      = __float2bfloat16(f[0][t] * wv);
        qo[qk + 16 + ccol] = __float2bfloat16(f[1][t] * wv);
        ko[qk + ccol]      = __float2bfloat16(f[2][t]);
        ko[qk + 16 + ccol] = __float2bfloat16(f[3][t]);
        vs[row][ccol]      = bf_round(f[4][t]);
        vs[row][16 + ccol] = bf_round(f[5][t]);
    }
    __syncthreads();
#pragma unroll
    for (int l = 0; l < 8; ++l) {
        int idx = l * 256 + tid;
        int d = idx >> 6, nn = idx & 63;
        vt[((size_t)r * 32 + d) * 512 + n0 + nn] = vs[nn][d];
    }
}

// ---------------------------------------------------------------------------
// FALLBACK kernels: k_proj96 (mid), k_proj32 (low)
// ---------------------------------------------------------------------------
__global__ __launch_bounds__(256) void k_proj96(
    const float* __restrict__ x, const float* __restrict__ Wq,
    const float* __restrict__ Wkv, int h, const float* __restrict__ rowW,
    bf16* __restrict__ qo, bf16* __restrict__ ko, bf16* __restrict__ vo)
{
    __shared__ float xs[8][128];
    const int tid = threadIdx.x;
    const int row0 = blockIdx.x * 8;
#pragma unroll
    for (int l = 0; l < 4; ++l) {
        int idx = l * 256 + tid;
        int m = idx >> 7, k = idx & 127;
        xs[m][k] = x[(size_t)(row0 + m) * DIM_ + k];
    }
    __syncthreads();
    const int m = tid >> 5, d = tid & 31;
    const float* wq = Wq  + h * 32 + d;
    const float* wk = Wkv + h * 32 + d;
    const float* wv = Wkv + 256 + h * 32 + d;
    float aq = 0.0f, ak = 0.0f, av = 0.0f;
    for (int k = 0; k < 128; ++k) {
        float xv = xs[m][k];
        aq += xv * wq[k * 256];
        ak += xv * wk[k * 512];
        av += xv * wv[k * 512];
    }
    const int rowg = row0 + m;
    const int r = rowg >> 9, n = rowg & (N_ - 1);
    aq *= rowW[n * 128 + r];
    qo[((size_t)n * 128 + r) * 32 + d] = __float2bfloat16(aq);
    ko[((size_t)n * 128 + r) * 32 + d] = __float2bfloat16(ak);
    vo[((size_t)r * 32 + d) * 512 + n] = __float2bfloat16(av);
}

__global__ __launch_bounds__(256) void k_proj32(
    const float* __restrict__ x, const float* __restrict__ W,
    int ldw, int col0, bf16* __restrict__ out, int mode,
    const float* __restrict__ rowW)
{
    __shared__ float xs[8][128];
    const int tid = threadIdx.x;
    const int row0 = blockIdx.x * 8;
#pragma unroll
    for (int l = 0; l < 4; ++l) {
        int idx = l * 256 + tid;
        int m = idx >> 7, k = idx & 127;
        xs[m][k] = x[(size_t)(row0 + m) * DIM_ + k];
    }
    __syncthreads();
    const int m = tid >> 5, d = tid & 31;
    float acc = 0.0f;
    for (int k = 0; k < 128; ++k) acc += xs[m][k] * W[k * ldw + col0 + d];
    const int rowg = row0 + m;
    const int r = rowg >> 9, n = rowg & (N_ - 1);
    if (rowW) acc *= rowW[n * 128 + r];
    size_t o = (mode == 0) ? ((size_t)n * 128 + r) * 32 + d
                           : ((size_t)r * 512 + n) * 32 + d;
    out[o] = __float2bfloat16(acc);
}

// ---------------------------------------------------------------------------
// Per head (MFMA): dots[i][j] = base[i][j] + scale * sum_rd q[i][rd]*k[j][rd]
// ---------------------------------------------------------------------------
__global__ __launch_bounds__(256) void k_dots_mfma(
    const bf16* __restrict__ q_h, const bf16* __restrict__ k_h,
    const float* base, float* dots)
{
    const int tid  = threadIdx.x;
    const int wave = tid >> 6, lane = tid & 63;
    const int i0 = blockIdx.y * 64 + (wave >> 1) * 32;
    const int j0 = blockIdx.x * 64 + (wave & 1) * 32;
    const int lr = lane & 15;
    const int lk = (lane >> 4) * 8;

    const bf16* a0p = q_h + (((size_t)(i0 + lr))      << 12) + lk;
    const bf16* a1p = q_h + (((size_t)(i0 + 16 + lr)) << 12) + lk;
    const bf16* b0p = k_h + (((size_t)(j0 + lr))      << 12) + lk;
    const bf16* b1p = k_h + (((size_t)(j0 + 16 + lr)) << 12) + lk;

    facc4 acc00 = {}, acc01 = {}, acc10 = {}, acc11 = {};

#pragma unroll 4
    for (int k = 0; k < RD_; k += 32) {
        bfrag8 a0 = *(const bfrag8*)(a0p + k);
        bfrag8 a1 = *(const bfrag8*)(a1p + k);
        bfrag8 b0 = *(const bfrag8*)(b0p + k);
        bfrag8 b1 = *(const bfrag8*)(b1p + k);
        acc00 = __builtin_amdgcn_mfma_f32_16x16x32_bf16(a0, b0, acc00, 0, 0, 0);
        acc01 = __builtin_amdgcn_mfma_f32_16x16x32_bf16(a0, b1, acc01, 0, 0, 0);
        acc10 = __builtin_amdgcn_mfma_f32_16x16x32_bf16(a1, b0, acc10, 0, 0, 0);
        acc11 = __builtin_amdgcn_mfma_f32_16x16x32_bf16(a1, b1, acc11, 0, 0, 0);
    }

    const float scale = 0.17677669529663689f;   // 32^-0.5
    const int dr = (lane >> 4) * 4, dc = lane & 15;
#pragma unroll
    for (int t = 0; t < 4; ++t) {
        size_t i00 = (size_t)(i0 +      dr + t) * N_;
        size_t i16 = (size_t)(i0 + 16 + dr + t) * N_;
        dots[i00 + j0 +      dc] = base[i00 + j0 +      dc] + acc00[t] * scale;
        dots[i00 + j0 + 16 + dc] = base[i00 + j0 + 16 + dc] + acc01[t] * scale;
        dots[i16 + j0 +      dc] = base[i16 + j0 +      dc] + acc10[t] * scale;
        dots[i16 + j0 + 16 + dc] = base[i16 + j0 + 16 + dc] + acc11[t] * scale;
    }
}

// ---------------------------------------------------------------------------
// FALLBACK: row softmax over j, fp32 in place on dots [N][N]
// ---------------------------------------------------------------------------
__global__ __launch_bounds__(256) void k_smax(float* __restrict__ dots)
{
    __shared__ float red[4];
    const int i = blockIdx.x;
    const int t = threadIdx.x;
    float* p = dots + (size_t)i * N_;
    float a = p[t], b = p[t + 256];
    float m = fmaxf(a, b);
#pragma unroll
    for (int off = 32; off > 0; off >>= 1) m = fmaxf(m, __shfl_xor(m, off));
    if ((t & 63) == 0) red[t >> 6] = m;
    __syncthreads();
    m = fmaxf(fmaxf(red[0], red[1]), fmaxf(red[2], red[3]));
    float e0 = __expf(a - m), e1 = __expf(b - m);
    float s = e0 + e1;
#pragma unroll
    for (int off = 32; off > 0; off >>= 1) s += __shfl_xor(s, off);
    __syncthreads();
    if ((t & 63) == 0) red[t >> 6] = s;
    __syncthreads();
    s = red[0] + red[1] + red[2] + red[3];
    float inv = 1.0f / s;
    p[t] = e0 * inv;
    p[t + 256] = e1 * inv;
}

// ---------------------------------------------------------------------------
// row softmax -> SPLIT bf16 probs (hi | lo), into the dead pbh[h] plane
// ---------------------------------------------------------------------------
__global__ __launch_bounds__(256) void k_smax2(
    const float* __restrict__ dots, short* __restrict__ attn)
{
    __shared__ float red[4];
    const int i = blockIdx.x;
    const int t = threadIdx.x;
    const float* p = dots + (size_t)i * N_;
    float a = p[t], b = p[t + 256];
    float m = fmaxf(a, b);
#pragma unroll
    for (int off = 32; off > 0; off >>= 1) m = fmaxf(m, __shfl_xor(m, off));
    if ((t & 63) == 0) red[t >> 6] = m;
    __syncthreads();
    m = fmaxf(fmaxf(red[0], red[1]), fmaxf(red[2], red[3]));
    float e0 = __expf(a - m), e1 = __expf(b - m);
    float s = e0 + e1;
#pragma unroll
    for (int off = 32; off > 0; off >>= 1) s += __shfl_xor(s, off);
    __syncthreads();
    if ((t & 63) == 0) red[t >> 6] = s;
    __syncthreads();
    s = red[0] + red[1] + red[2] + red[3];
    float inv = 1.0f / s;
    float p0 = e0 * inv, p1 = e1 * inv;
    short h0 = bf_round(p0), h1 = bf_round(p1);
    attn[(size_t)i * N_ + t]             = h0;
    attn[(size_t)i * N_ + t + 256]       = h1;
    attn[NN_ + (size_t)i * N_ + t]       = bf_round(p0 - bf_tof(h0));
    attn[NN_ + (size_t)i * N_ + t + 256] = bf_round(p1 - bf_tof(h1));
}

// ---------------------------------------------------------------------------
// Per head (MFMA): om[r][i][h*32+d] = sum_j P[i][j] * v[r][j][d]
// ---------------------------------------------------------------------------
__global__ __launch_bounds__(256) void k_av_mfma(
    const short* __restrict__ attn, const bf16* __restrict__ vt,
    bf16* __restrict__ om, int h)
{
    const int tid = threadIdx.x;
    const int wave = tid >> 6, lane = tid & 63;
    const int r = blockIdx.y;
    const int i0 = blockIdx.x * 64 + wave * 16;
    const int lr = lane & 15, lk = (lane >> 4) * 8;

    const short* pah = attn + (size_t)(i0 + lr) * N_ + lk;
    const short* pal = pah + NN_;
    const short* pb0 = (const short*)vt + ((size_t)r * 32 + lr) * N_ + lk;
    const short* pb1 = pb0 + 16 * N_;

    facc4 acc0 = {}, acc1 = {};
#pragma unroll 4
    for (int k = 0; k < N_; k += 32) {
        bfrag8 ah = *(const bfrag8*)(pah + k);
        bfrag8 al = *(const bfrag8*)(pal + k);
        bfrag8 b0 = *(const bfrag8*)(pb0 + k);
        bfrag8 b1 = *(const bfrag8*)(pb1 + k);
        acc0 = __builtin_amdgcn_mfma_f32_16x16x32_bf16(ah, b0, acc0, 0, 0, 0);
        acc0 = __builtin_amdgcn_mfma_f32_16x16x32_bf16(al, b0, acc0, 0, 0, 0);
        acc1 = __builtin_amdgcn_mfma_f32_16x16x32_bf16(ah, b1, acc1, 0, 0, 0);
        acc1 = __builtin_amdgcn_mfma_f32_16x16x32_bf16(al, b1, acc1, 0, 0, 0);
    }
    const int crow = (lane >> 4) * 4, ccol = lane & 15;
#pragma unroll
    for (int t = 0; t < 4; ++t) {
        size_t ob = ((size_t)r * N_ + i0 + crow + t) * INNER_ + h * 32;
        om[ob + ccol]      = __float2bfloat16(acc0[t]);
        om[ob + 16 + ccol] = __float2bfloat16(acc1[t]);
    }
}

// ---------------------------------------------------------------------------
// FALLBACK: per-head AV, fp32 VALU, v layout [r][32][n] (transposed vt!)
// NOTE: low path uses k_av_h with the OLD [r][j][d] layout.
// ---------------------------------------------------------------------------
__global__ __launch_bounds__(256) void k_av_h(
    const float* __restrict__ attn, const bf16* __restrict__ v_h,
    bf16* __restrict__ om, int h)
{
    __shared__ float as[64][66];
    __shared__ float vs[64][34];
    const int tid = threadIdx.x;
    const int it = blockIdx.x, r = blockIdx.y;
    const int i0 = it * 64;
    const int ti = tid >> 4, td = tid & 15;
    float acc[4][2] = {};

    for (int j0 = 0; j0 < N_; j0 += 64) {
#pragma unroll
        for (int l = 0; l < 4; ++l) {
            int idx = l * 256 + tid;
            int i = idx >> 4, j4 = idx & 15;
            float4 u = *(const float4*)(attn + (size_t)(i0 + i) * N_ + j0 + j4 * 4);
            float* d = &as[i][j4 * 4];
            d[0] = u.x; d[1] = u.y; d[2] = u.z; d[3] = u.w;
        }
        {
            int j = tid >> 2, ck = tid & 3;
            uint4 u = *(const uint4*)(v_h + ((size_t)r * N_ + j0 + j) * 32 + ck * 8);
            float* d = &vs[j][ck * 8];
            d[0] = bf_lo(u.x); d[1] = bf_hi(u.x); d[2] = bf_lo(u.y); d[3] = bf_hi(u.y);
            d[4] = bf_lo(u.z); d[5] = bf_hi(u.z); d[6] = bf_lo(u.w); d[7] = bf_hi(u.w);
        }
        __syncthreads();
#pragma unroll 8
        for (int jj = 0; jj < 64; jj += 2) {
            float2 b0 = *(const float2*)&vs[jj][td * 2];
            float2 b1 = *(const float2*)&vs[jj + 1][td * 2];
#pragma unroll
            for (int i = 0; i < 4; ++i) {
                float2 a = *(const float2*)&as[ti * 4 + i][jj];
                acc[i][0] += a.x * b0.x + a.y * b1.x;
                acc[i][1] += a.x * b0.y + a.y * b1.y;
            }
        }
        __syncthreads();
    }
#pragma unroll
    for (int ii = 0; ii < 4; ++ii) {
        bf16* op = om + ((size_t)r * N_ + i0 + ti * 4 + ii) * INNER_ + h * 32 + td * 2;
        op[0] = __float2bfloat16(acc[ii][0]);
        op[1] = __float2bfloat16(acc[ii][1]);
    }
}

// ---------------------------------------------------------------------------
// Final projection via MFMA: out = om @ Wout + b_out, IN PLACE on d_out.
// ---------------------------------------------------------------------------
__global__ __launch_bounds__(256) void k_final_mfma(
    const bf16* om, const short* __restrict__ wo_hi,
    const short* __restrict__ wo_lo, const float* __restrict__ b_out,
    float* out)
{
    const int tid = threadIdx.x;
    const int wave = tid >> 6, lane = tid & 63;
    const int lr = lane & 15, lko = (lane >> 4) * 8;
    const int rowb = blockIdx.x * 64;
    const short* ap = (const short*)om + (size_t)(rowb + wave * 16 + lr) * 256 + lko;

    facc4 f[8] = {};
#pragma unroll
    for (int ks = 0; ks < 8; ++ks) {
        bfrag8 a = *(const bfrag8*)(ap + ks * 32);
#pragma unroll
        for (int ct = 0; ct < 8; ++ct) {
            bfrag8 bh = *(const bfrag8*)(wo_hi + (ct * 16 + lr) * 256 + ks * 32 + lko);
            bfrag8 bl = *(const bfrag8*)(wo_lo + (ct * 16 + lr) * 256 + ks * 32 + lko);
            f[ct] = __builtin_amdgcn_mfma_f32_16x16x32_bf16(a, bh, f[ct], 0, 0, 0);
            f[ct] = __builtin_amdgcn_mfma_f32_16x16x32_bf16(a, bl, f[ct], 0, 0, 0);
        }
    }
    const int crow = (lane >> 4) * 4, ccol = lane & 15;
#pragma unroll
    for (int ct = 0; ct < 8; ++ct) {
        int c = ct * 16 + ccol;
        float bb = b_out[c];
#pragma unroll
        for (int t = 0; t < 4; ++t) {
            int row = rowb + wave * 16 + crow + t;
            out[(size_t)row * 128 + c] = f[ct][t] + bb;
        }
    }
}

// ---------------------------------------------------------------------------
// FALLBACK: out = om @ Wout + b_out, fp32 VALU, in place
// ---------------------------------------------------------------------------
__global__ __launch_bounds__(256) void k_final(
    const bf16* om, const float* __restrict__ Wout,
    const float* __restrict__ b_out, float* out)
{
    __shared__ float as[64][68];
    __shared__ float ws[64][132];
    const int tid = threadIdx.x;
    const int row0 = blockIdx.x * 64;
    const int tm = tid >> 5, tc = tid & 31;
    float acc[8][4] = {};

    for (int k0 = 0; k0 < INNER_; k0 += 64) {
#pragma unroll
        for (int l = 0; l < 2; ++l) {
            int idx = l * 256 + tid;
            int m = idx >> 3, ck = idx & 7;
            uint4 u = *(const uint4*)(om + (size_t)(row0 + m) * INNER_ + k0 + ck * 8);
            float* d = &as[m][ck * 8];
            d[0] = bf_lo(u.x); d[1] = bf_hi(u.x); d[2] = bf_lo(u.y); d[3] = bf_hi(u.y);
            d[4] = bf_lo(u.z); d[5] = bf_hi(u.z); d[6] = bf_lo(u.w); d[7] = bf_hi(u.w);
        }
#pragma unroll
        for (int l = 0; l < 8; ++l) {
            int idx = l * 256 + tid;
            int kk = idx >> 5, c4 = idx & 31;
            float4 u = *(const float4*)(Wout + (size_t)(k0 + kk) * DIM_ + c4 * 4);
            float* d = &ws[kk][c4 * 4];
            d[0] = u.x; d[1] = u.y; d[2] = u.z; d[3] = u.w;
        }
        __syncthreads();
        for (int kk = 0; kk < 64; kk += 2) {
            float4 b0 = *(const float4*)&ws[kk][tc * 4];
            float4 b1 = *(const float4*)&ws[kk + 1][tc * 4];
#pragma unroll
            for (int i = 0; i < 8; ++i) {
                float2 a = *(const float2*)&as[tm * 8 + i][kk];
                acc[i][0] += a.x * b0.x + a.y * b1.x;
                acc[i][1] += a.x * b0.y + a.y * b1.y;
                acc[i][2] += a.x * b0.z + a.y * b1.z;
                acc[i][3] += a.x * b0.w + a.y * b1.w;
            }
        }
        __syncthreads();
    }
#pragma unroll
    for (int ii = 0; ii < 8; ++ii) {
        int rowg = row0 + tm * 8 + ii;
#pragma unroll
        for (int jj = 0; jj < 4; ++jj) {
            int cg = tc * 4 + jj;
            out[(size_t)rowg * DIM_ + cg] = acc[ii][jj] + b_out[cg];
        }
    }
}

// ---------------------------------------------------------------------------
// Workspace arena.
// NEW path (ws >= 41,754,688 B):
//   [0         ..  1,048,576)  dots   [N][N] fp32
//   [1,048,576 ..  3,145,728)  sw_all [8][N][R] fp32 (-> wrow in place)
//   [3,145,728 ..  3,407,872)  qsw    [N][128] fp32
//   [3,407,872 ..  7,602,176)  q_h    [N][R][32] bf16 (per-head, wrow-scaled)
//   [7,602,176 .. 11,796,480)  k_h    [N][R][32] bf16 (per-head)
//   [11,796,480.. 15,990,784)  v_h    [R][32][N] bf16 (per-head, transposed)
//   [15,990,784.. 24,379,392)  pbh    [8][N][N] fp32; plane h recycled as attn
//   [24,379,392.. 41,156,608)  xbf    [65536][128] bf16
//   [41,156,608.. 41,754,688)  weight preps (wqkv/wout/wksw hi+lo, pbw, G, B)
// MID path (ws >= 22,544,384): round-3 layout/pipeline.
// LOW path (ws >= 9,961,472): original per-head fallback.
// om (bf16, 33.55 MB) lives in d_out; final converts to fp32 in place.
// ---------------------------------------------------------------------------
extern "C" void kernel_launch(void* const* d_in, const int* in_sizes, int n_in,
                              void* d_out, int out_size, void* d_ws, size_t ws_size,
                              hipStream_t stream)
{
    static const int exp_sizes[13] = {8388608, 33554432, 32768, 65536, 32768,
                                      128, 128, 128, 1024, 16384, 128, 16384, 128};
    const size_t WS_MIN = 9961472ULL;
    const size_t WS_BIG = 22544384ULL;
    const size_t WS_NEW = 41754688ULL;
    float sentinel = 0.0f;
    if (n_in != 13) sentinel = 5e7f;
    else {
        for (int i = 0; i < 13; ++i)
            if (in_sizes[i] != exp_sizes[i]) { sentinel = 1e6f * (float)(i + 1); break; }
    }
    if (sentinel == 0.0f && out_size != 8388608) sentinel = 6e7f;
    if (sentinel == 0.0f && ws_size < WS_MIN) sentinel = 1e8f + (float)ws_size;
    if (sentinel != 0.0f) {
        k_sentinel<<<1, 1, 0, stream>>>((float*)d_out, sentinel);
        return;
    }

    const float* x     = (const float*)d_in[0];
    const float* pair  = (const float*)d_in[1];
    const float* Wq    = (const float*)d_in[2];
    const float* Wkv   = (const float*)d_in[3];
    const float* Wout  = (const float*)d_in[4];
    const float* b_out = (const float*)d_in[5];
    const float* ln_g  = (const float*)d_in[6];
    const float* ln_b  = (const float*)d_in[7];
    const float* Wpair = (const float*)d_in[8];
    const float* Wq_sw = (const float*)d_in[9];
    const float* bq_sw = (const float*)d_in[10];
    const float* Wk_sw = (const float*)d_in[11];
    const float* bk_sw = (const float*)d_in[12];

    char* w = (char*)d_ws;
    bf16* om = (bf16*)d_out;

    if (ws_size >= WS_NEW) {
        float* dots   = (float*)(w);
        float* sw_all = (float*)(w + 1048576ULL);
        float* qsw    = (float*)(w + 3145728ULL);
        bf16*  q_h    = (bf16*)(w + 3407872ULL);
        bf16*  k_h    = (bf16*)(w + 7602176ULL);
        bf16*  v_h    = (bf16*)(w + 11796480ULL);
        float* pbh    = (float*)(w + 15990784ULL);
        short* xbf    = (short*)(w + 24379392ULL);
        short* wqkv_hi = (short*)(w + 41156608ULL);   // 196,608 B
        short* wqkv_lo = (short*)(w + 41353216ULL);   // 196,608 B
        short* wo_hi   = (short*)(w + 41549824ULL);   //  65,536 B
        short* wo_lo   = (short*)(w + 41615360ULL);   //  65,536 B
        short* wk_hi   = (short*)(w + 41680896ULL);   //  32,768 B
        short* wk_lo   = (short*)(w + 41713664ULL);   //  32,768 B
        short* pbw_hi  = (short*)(w + 41746432ULL);   //   4,096 B
        short* pbw_lo  = (short*)(w + 41750528ULL);   //   4,096 B
        float* Gc      = (float*)(w + 41754624ULL);   //      32 B
        float* Bc      = (float*)(w + 41754656ULL);   //      32 B

        k_xbf     <<<dim3(4096), 256, 0, stream>>>(x, xbf);
        k_qsw     <<<dim3(512),  128, 0, stream>>>(x, Wq_sw, bq_sw, qsw);
        k_prep_all<<<dim3(576),  256, 0, stream>>>(Wq, Wkv, Wout, Wk_sw,
                                                   wqkv_hi, wqkv_lo, wo_hi, wo_lo,
                                                   wk_hi, wk_lo);
        k_prep    <<<dim3(1),    128, 0, stream>>>(ln_g, ln_b, Wpair, pbw_hi, pbw_lo, Gc, Bc);
        k_pb_mfma <<<dim3(4096), 256, 0, stream>>>(pair, pbw_hi, pbw_lo, Gc, Bc, pbh);
        k_swk     <<<dim3(1024), 256, 0, stream>>>(xbf, wk_hi, wk_lo, bk_sw, qsw, sw_all);
        k_wrow2   <<<dim3(4096), 128, 0, stream>>>(sw_all);

        for (int h = 0; h < H_; ++h) {
            short* attn = (short*)(pbh + (size_t)h * NN_);  // plane recycled
            k_proj_mfma<<<dim3(1024),  256, 0, stream>>>(xbf, wqkv_hi, wqkv_lo, h,
                                                         sw_all + (size_t)h * 65536,
                                                         q_h, k_h, (short*)v_h);
            k_dots_mfma<<<dim3(8, 8),  256, 0, stream>>>(q_h, k_h, pbh + (size_t)h * NN_, dots);
            k_smax2    <<<dim3(512),   256, 0, stream>>>(dots, attn);
            k_av_mfma  <<<dim3(8, 128),256, 0, stream>>>(attn, v_h, om, h);
        }
        k_final_mfma<<<dim3(1024), 256, 0, stream>>>(om, wo_hi, wo_lo, b_out, (float*)d_out);

    } else if (ws_size >= WS_BIG) {
        float* dots = (float*)(w);
        float* sw   = (float*)(w + 1048576ULL);
        float* qsw  = (float*)(w + 1310720ULL);
        bf16*  q_h  = (bf16*)(w + 1572864ULL);
        bf16*  k_h  = (bf16*)(w + 5767168ULL);
        bf16*  v_h  = (bf16*)(w + 9961472ULL);
        float* pbh  = (float*)(w + 14155776ULL);

        short* wgt_hi = (short*)dots;
        short* wgt_lo = (short*)dots + 2048;
        float* Gc     = dots + 2048;
        float* Bc     = dots + 2056;

        k_qsw    <<<dim3(512),  128, 0, stream>>>(x, Wq_sw, bq_sw, qsw);
        k_prep   <<<dim3(1),    128, 0, stream>>>(ln_g, ln_b, Wpair, wgt_hi, wgt_lo, Gc, Bc);
        k_pb_mfma<<<dim3(4096), 256, 0, stream>>>(pair, wgt_hi, wgt_lo, Gc, Bc, pbh);

        for (int h = 0; h < H_; ++h) {
            short* attn = (short*)(pbh + (size_t)h * NN_);
            k_sw_h  <<<dim3(256),    256, 0, stream>>>(x, Wk_sw, bk_sw, qsw, sw, h);
            k_wrow2 <<<dim3(512),    128, 0, stream>>>(sw);
            k_proj96<<<dim3(8192),   256, 0, stream>>>(x, Wq, Wkv, h, sw, q_h, k_h, v_h);
            k_dots_mfma<<<dim3(8, 8),256, 0, stream>>>(q_h, k_h, pbh + (size_t)h * NN_, dots);
            k_smax2 <<<dim3(512),    256, 0, stream>>>(dots, attn);
            k_av_mfma<<<dim3(8, 128),256, 0, stream>>>(attn, v_h, om, h);
        }
        k_final<<<dim3(1024), 256, 0, stream>>>(om, Wout, b_out, (float*)d_out);

    } else {
        float* dots = (float*)(w);
        float* sw   = (float*)(w + 1048576ULL);
        float* qsw  = (float*)(w + 1310720ULL);
        bf16*  q_h  = (bf16*)(w + 1572864ULL);
        bf16*  k_h  = (bf16*)(w + 5767168ULL);
        bf16*  v_h  = k_h;   // alias (k dead after k_dots_mfma)

        k_qsw<<<dim3(512), 128, 0, stream>>>(x, Wq_sw, bq_sw, qsw);
        for (int h = 0; h < H_; ++h) {
            k_pb_h  <<<dim3(65536),  256, 0, stream>>>(pair, ln_g, ln_b, Wpair, dots, h);
            k_sw_h  <<<dim3(256),    256, 0, stream>>>(x, Wk_sw, bk_sw, qsw, sw, h);
            k_wrow2 <<<dim3(512),    128, 0, stream>>>(sw);
            k_proj32<<<dim3(8192),   256, 0, stream>>>(x, Wq,  256, h * 32,       q_h, 0, sw);
            k_proj32<<<dim3(8192),   256, 0, stream>>>(x, Wkv, 512, h * 32,       k_h, 0, nullptr);
            k_dots_mfma<<<dim3(8, 8),256, 0, stream>>>(q_h, k_h, dots, dots);
            k_smax  <<<dim3(512),    256, 0, stream>>>(dots);
            k_proj32<<<dim3(8192),   256, 0, stream>>>(x, Wkv, 512, 256 + h * 32, v_h, 1, nullptr);
            k_av_h  <<<dim3(8, 128), 256, 0, stream>>>(dots, v_h, om, h);
        }
        k_final<<<dim3(1024), 256, 0, stream>>>(om, Wout, b_out, (float*)d_out);
    }
}